// Round 1
// baseline (1029.265 us; speedup 1.0000x reference)
//
#include <hip/hip_runtime.h>

// Problem constants (match reference)
#define N_NODES 50000
#define N_EDGES 800000
#define HID 128          // HEADS*HEAD_DIM
#define NEG_SLOPE 0.2f
#define BN_EPS 1e-5f

// ---------------------------------------------------------------------------
// K0: init acc = bias0+bias1 (broadcast per column), zero den0/den1
// ---------------------------------------------------------------------------
__global__ __launch_bounds__(256) void k_init(float* __restrict__ acc,
                                              const float* __restrict__ b0,
                                              const float* __restrict__ b1,
                                              float* __restrict__ den0,
                                              float* __restrict__ den1) {
    int stride = gridDim.x * blockDim.x;
    int idx0 = blockIdx.x * blockDim.x + threadIdx.x;
    for (int i = idx0; i < N_NODES * HID; i += stride)
        acc[i] = b0[i & 127] + b1[i & 127];
    for (int i = idx0; i < N_NODES * 2; i += stride) {
        den0[i] = 0.f;
        den1[i] = 0.f;
    }
}

// ---------------------------------------------------------------------------
// K1: fused GEMM  C[m, 0:384] = x[m,:] @ {fc_w0, fc_w1, skip_w}^T
//     64x64 tile, full K=128 staged in LDS, 4x4 register micro-tile.
//     jblk 0..1 -> fc_w0 (f0), 2..3 -> fc_w1 (f1), 4..5 -> skip_w (+skip_b -> hs)
// ---------------------------------------------------------------------------
__global__ __launch_bounds__(256) void k_gemm3(const float* __restrict__ x,
                                               const float* __restrict__ w0,
                                               const float* __restrict__ w1,
                                               const float* __restrict__ wsk,
                                               const float* __restrict__ skip_b,
                                               float* __restrict__ f0,
                                               float* __restrict__ f1,
                                               float* __restrict__ hs) {
    __shared__ float As[64][132];   // stride 132: 16B-aligned rows, rotates banks
    __shared__ float Bs[64][132];

    int tid = threadIdx.x;                 // 0..255
    int m0 = blockIdx.y * 64;
    int jblk = blockIdx.x;                 // 0..5
    const float* W = (jblk < 2) ? w0 : (jblk < 4) ? w1 : wsk;
    int j0 = (jblk & 1) * 64;              // col offset within the 128-wide matrix

    // cooperative load: 64 rows x 32 float4 each for A and B
    for (int i = 0; i < 8; i++) {
        int idx = tid * 8 + i;             // 0..2047
        int row = idx >> 5;
        int c4 = idx & 31;
        float4 v = make_float4(0.f, 0.f, 0.f, 0.f);
        int gr = m0 + row;
        if (gr < N_NODES) v = *(const float4*)(x + (size_t)gr * HID + c4 * 4);
        *(float4*)(&As[row][c4 * 4]) = v;
        float4 wv = *(const float4*)(W + (size_t)(j0 + row) * HID + c4 * 4);
        *(float4*)(&Bs[row][c4 * 4]) = wv;
    }
    __syncthreads();

    int tx = tid & 15, ty = tid >> 4;      // 16x16 thread grid
    float acc[4][4] = {};
    for (int k = 0; k < 128; k += 4) {
        float4 a[4], b[4];
#pragma unroll
        for (int i = 0; i < 4; i++) a[i] = *(const float4*)(&As[ty + 16 * i][k]);
#pragma unroll
        for (int j = 0; j < 4; j++) b[j] = *(const float4*)(&Bs[tx + 16 * j][k]);
#pragma unroll
        for (int i = 0; i < 4; i++)
#pragma unroll
            for (int j = 0; j < 4; j++)
                acc[i][j] += a[i].x * b[j].x + a[i].y * b[j].y +
                             a[i].z * b[j].z + a[i].w * b[j].w;
    }

    float* dstp = (jblk < 2) ? f0 : (jblk < 4) ? f1 : hs;
#pragma unroll
    for (int i = 0; i < 4; i++) {
        int gr = m0 + ty + 16 * i;
        if (gr >= N_NODES) continue;
#pragma unroll
        for (int j = 0; j < 4; j++) {
            int col = j0 + tx + 16 * j;
            float v = acc[i][j];
            if (jblk >= 4) v += skip_b[col];
            dstp[(size_t)gr * HID + col] = v;
        }
    }
}

// ---------------------------------------------------------------------------
// K1b: el/er = sum_d f[n,h,d] * attn_{l,r}[h,d]   (wave per (node,head))
// ---------------------------------------------------------------------------
__global__ __launch_bounds__(256) void k_attn_dots(const float* __restrict__ f0,
                                                   const float* __restrict__ f1,
                                                   const float* __restrict__ al0,
                                                   const float* __restrict__ ar0,
                                                   const float* __restrict__ al1,
                                                   const float* __restrict__ ar1,
                                                   float* __restrict__ el0,
                                                   float* __restrict__ er0,
                                                   float* __restrict__ el1,
                                                   float* __restrict__ er1) {
    int wave = threadIdx.x >> 6;
    int lane = threadIdx.x & 63;
    int n = blockIdx.x * 2 + (wave >> 1);
    int h = wave & 1;
    if (n >= N_NODES) return;
    int c = h * 64 + lane;                 // attn arrays are [H,D] flat = [128]
    float v0 = f0[(size_t)n * HID + c];
    float v1 = f1[(size_t)n * HID + c];
    float s0 = v0 * al0[c], s1 = v0 * ar0[c];
    float s2 = v1 * al1[c], s3 = v1 * ar1[c];
#pragma unroll
    for (int m = 32; m; m >>= 1) {
        s0 += __shfl_xor(s0, m);
        s1 += __shfl_xor(s1, m);
        s2 += __shfl_xor(s2, m);
        s3 += __shfl_xor(s3, m);
    }
    if (lane == 0) {
        el0[n * 2 + h] = s0;
        er0[n * 2 + h] = s1;
        el1[n * 2 + h] = s2;
        er1[n * 2 + h] = s3;
    }
}

// ---------------------------------------------------------------------------
// K2: per (edge, head): ex = exp(leaky(el[src]+er[dst])); den[dst] += ex
//     (no max-shift: |e| <~ 8, exp bounded, identical within f32 tolerance)
// ---------------------------------------------------------------------------
__global__ __launch_bounds__(256) void k_edge_pass1(const int* __restrict__ src,
                                                    const int* __restrict__ dst,
                                                    const float* __restrict__ el,
                                                    const float* __restrict__ er,
                                                    float* __restrict__ exbuf,
                                                    float* __restrict__ den) {
    int gid = blockIdx.x * 256 + threadIdx.x;
    if (gid >= N_EDGES * 2) return;
    int e = gid >> 1, h = gid & 1;
    int s = src[e], d = dst[e];
    float ev = el[s * 2 + h] + er[d * 2 + h];
    ev = (ev > 0.f) ? ev : ev * NEG_SLOPE;
    float ex = expf(ev);
    exbuf[gid] = ex;
    unsafeAtomicAdd(&den[d * 2 + h], ex);
}

// ---------------------------------------------------------------------------
// K3: per (edge, c): acc[dst, c] += (ex/den[dst]*ew) * f[src, c]
// ---------------------------------------------------------------------------
__global__ __launch_bounds__(256) void k_edge_pass2(const int* __restrict__ src,
                                                    const int* __restrict__ dst,
                                                    const float* __restrict__ ew,
                                                    const float* __restrict__ exbuf,
                                                    const float* __restrict__ den,
                                                    const float* __restrict__ f,
                                                    float* __restrict__ acc) {
    int gid = blockIdx.x * 256 + threadIdx.x;   // E*128 = 102.4M < 2^31
    int c = gid & 127;
    int e = gid >> 7;
    int h = c >> 6;
    int s = src[e], d = dst[e];
    float alpha = exbuf[e * 2 + h] / den[d * 2 + h] * ew[e];
    unsafeAtomicAdd(&acc[(size_t)d * HID + c], alpha * f[(size_t)s * HID + c]);
}

// ---------------------------------------------------------------------------
// K4: h = hs + relu(acc) (in place over hs); per-column partial sums (double)
//     Launch with EXACTLY 512 blocks x 256 threads.
// ---------------------------------------------------------------------------
__global__ __launch_bounds__(256) void k_h_bn(float* __restrict__ h,
                                              const float* __restrict__ acc,
                                              double* __restrict__ psum,
                                              double* __restrict__ psumsq) {
    int tid = threadIdx.x;
    double s = 0.0, q = 0.0;
    const int total = N_NODES * HID;
    const int stride = 512 * 256;               // multiple of 128: c fixed/thread
    for (int idx = blockIdx.x * 256 + tid; idx < total; idx += stride) {
        float a = acc[idx];
        float v = h[idx] + fmaxf(a, 0.f);
        h[idx] = v;
        s += v;
        q += (double)v * v;
    }
    __shared__ double ls[256], lq[256];
    ls[tid] = s;
    lq[tid] = q;
    __syncthreads();
    if (tid < 128) {                             // tid and tid+128 share column
        psum[blockIdx.x * 128 + tid] = ls[tid] + ls[tid + 128];
        psumsq[blockIdx.x * 128 + tid] = lq[tid] + lq[tid + 128];
    }
}

// ---------------------------------------------------------------------------
// K5: finalize BN: scale/shift per column. 1 block x 128 threads.
// ---------------------------------------------------------------------------
__global__ void k_bn_finalize(const double* __restrict__ psum,
                              const double* __restrict__ psumsq,
                              const float* __restrict__ gamma,
                              const float* __restrict__ beta,
                              float* __restrict__ ss) {
    int c = threadIdx.x;
    double s = 0.0, q = 0.0;
    for (int b = 0; b < 512; b++) {
        s += psum[b * 128 + c];
        q += psumsq[b * 128 + c];
    }
    double mu = s / N_NODES;
    double var = q / N_NODES - mu * mu;
    float sc = gamma[c] * (float)(1.0 / sqrt(var + (double)BN_EPS));
    ss[c] = sc;
    ss[128 + c] = beta[c] - (float)mu * sc;
}

// ---------------------------------------------------------------------------
// K6: logits[n,k] = relu(h*scale+shift) . clf_w[k,:] + clf_b[k]
//     wave per node, 16 shfl-reduced dots
// ---------------------------------------------------------------------------
__global__ __launch_bounds__(256) void k_classify(const float* __restrict__ h,
                                                  const float* __restrict__ ss,
                                                  const float* __restrict__ clf_w,
                                                  const float* __restrict__ clf_b,
                                                  float* __restrict__ out) {
    int wave = threadIdx.x >> 6, lane = threadIdx.x & 63;
    int n = blockIdx.x * 4 + wave;
    if (n >= N_NODES) return;
    float v0 = h[(size_t)n * HID + lane] * ss[lane] + ss[128 + lane];
    float v1 = h[(size_t)n * HID + 64 + lane] * ss[64 + lane] + ss[192 + lane];
    v0 = fmaxf(v0, 0.f);
    v1 = fmaxf(v1, 0.f);
#pragma unroll
    for (int k = 0; k < 16; k++) {
        float p = v0 * clf_w[k * 128 + lane] + v1 * clf_w[k * 128 + 64 + lane];
#pragma unroll
        for (int m = 32; m; m >>= 1) p += __shfl_xor(p, m);
        if (lane == 0) out[(size_t)n * 16 + k] = p + clf_b[k];
    }
}

// ---------------------------------------------------------------------------
extern "C" void kernel_launch(void* const* d_in, const int* in_sizes, int n_in,
                              void* d_out, int out_size, void* d_ws, size_t ws_size,
                              hipStream_t stream) {
    (void)in_sizes; (void)n_in; (void)out_size; (void)ws_size;
    const float* x      = (const float*)d_in[0];
    const int*   src0   = (const int*)d_in[1];
    const int*   dst0   = (const int*)d_in[2];
    const float* ew0    = (const float*)d_in[3];
    const int*   src1   = (const int*)d_in[4];
    const int*   dst1   = (const int*)d_in[5];
    const float* ew1    = (const float*)d_in[6];
    const float* fc_w0  = (const float*)d_in[7];
    const float* bias0  = (const float*)d_in[8];
    const float* al0    = (const float*)d_in[9];
    const float* ar0    = (const float*)d_in[10];
    const float* fc_w1  = (const float*)d_in[11];
    const float* bias1  = (const float*)d_in[12];
    const float* al1    = (const float*)d_in[13];
    const float* ar1    = (const float*)d_in[14];
    const float* skip_w = (const float*)d_in[15];
    const float* skip_b = (const float*)d_in[16];
    const float* gamma  = (const float*)d_in[17];
    const float* beta   = (const float*)d_in[18];
    const float* clf_w  = (const float*)d_in[19];
    const float* clf_b  = (const float*)d_in[20];
    float* out = (float*)d_out;

    char* wsp = (char*)d_ws;
    size_t off = 0;
    auto alloc = [&](size_t bytes) -> char* {
        char* p = wsp + off;
        off += (bytes + 255) & ~(size_t)255;
        return p;
    };
    float*  f0     = (float*)alloc((size_t)N_NODES * HID * 4);
    float*  f1     = (float*)alloc((size_t)N_NODES * HID * 4);
    float*  hs     = (float*)alloc((size_t)N_NODES * HID * 4);   // becomes h
    float*  acc    = (float*)alloc((size_t)N_NODES * HID * 4);
    float*  el0    = (float*)alloc((size_t)N_NODES * 2 * 4);
    float*  er0    = (float*)alloc((size_t)N_NODES * 2 * 4);
    float*  el1    = (float*)alloc((size_t)N_NODES * 2 * 4);
    float*  er1    = (float*)alloc((size_t)N_NODES * 2 * 4);
    float*  den0   = (float*)alloc((size_t)N_NODES * 2 * 4);
    float*  den1   = (float*)alloc((size_t)N_NODES * 2 * 4);
    float*  exbuf  = (float*)alloc((size_t)N_EDGES * 2 * 4);     // reused per relation
    double* psum   = (double*)alloc((size_t)512 * 128 * 8);
    double* psumsq = (double*)alloc((size_t)512 * 128 * 8);
    float*  ss     = (float*)alloc(256 * 4);

    k_init<<<2048, 256, 0, stream>>>(acc, bias0, bias1, den0, den1);

    dim3 g1(6, (N_NODES + 63) / 64);
    k_gemm3<<<g1, 256, 0, stream>>>(x, fc_w0, fc_w1, skip_w, skip_b, f0, f1, hs);

    k_attn_dots<<<(N_NODES + 1) / 2, 256, 0, stream>>>(f0, f1, al0, ar0, al1, ar1,
                                                       el0, er0, el1, er1);

    int g_e1 = (N_EDGES * 2 + 255) / 256;
    int g_e2 = (int)(((size_t)N_EDGES * 128) / 256);

    // relation 0
    k_edge_pass1<<<g_e1, 256, 0, stream>>>(src0, dst0, el0, er0, exbuf, den0);
    k_edge_pass2<<<g_e2, 256, 0, stream>>>(src0, dst0, ew0, exbuf, den0, f0, acc);
    // relation 1 (exbuf reuse is safe: same-stream ordering)
    k_edge_pass1<<<g_e1, 256, 0, stream>>>(src1, dst1, el1, er1, exbuf, den1);
    k_edge_pass2<<<g_e2, 256, 0, stream>>>(src1, dst1, ew1, exbuf, den1, f1, acc);

    k_h_bn<<<512, 256, 0, stream>>>(hs, acc, psum, psumsq);
    k_bn_finalize<<<1, 128, 0, stream>>>(psum, psumsq, gamma, beta, ss);
    k_classify<<<(N_NODES + 3) / 4, 256, 0, stream>>>(hs, ss, clf_w, clf_b, out);
}

// Round 2
// 838.397 us; speedup vs baseline: 1.2277x; 1.2277x over previous
//
#include <hip/hip_runtime.h>

// Problem constants (match reference)
#define N_NODES 50000
#define N_EDGES 800000
#define HID 128          // HEADS*HEAD_DIM
#define NEG_SLOPE 0.2f
#define BN_EPS 1e-5f

__device__ __forceinline__ float leaky(float v) {
    return (v > 0.f) ? v : v * NEG_SLOPE;
}

// ---------------------------------------------------------------------------
// K_zero: zero the per-node degree counters for both relations
// ---------------------------------------------------------------------------
__global__ __launch_bounds__(256) void k_zero(int* __restrict__ deg0,
                                              int* __restrict__ deg1) {
    int i = blockIdx.x * 256 + threadIdx.x;
    if (i < N_NODES) {
        deg0[i] = 0;
        deg1[i] = 0;
    }
}

// ---------------------------------------------------------------------------
// K_count: in-degree histogram per dst, both relations
// ---------------------------------------------------------------------------
__global__ __launch_bounds__(256) void k_count(const int* __restrict__ dst0,
                                               const int* __restrict__ dst1,
                                               int* __restrict__ deg0,
                                               int* __restrict__ deg1) {
    int e = blockIdx.x * 256 + threadIdx.x;
    if (e < N_EDGES) {
        atomicAdd(&deg0[dst0[e]], 1);
        atomicAdd(&deg1[dst1[e]], 1);
    }
}

// ---------------------------------------------------------------------------
// K_scan: exclusive prefix sum over 50000 degrees. gridDim.x = 2 (relation).
//         1024 threads, each owns a 49-element chunk; Hillis-Steele on sums.
// ---------------------------------------------------------------------------
__global__ __launch_bounds__(1024) void k_scan(const int* __restrict__ deg0,
                                               const int* __restrict__ deg1,
                                               int* __restrict__ offs0,
                                               int* __restrict__ offs1,
                                               int* __restrict__ cur0,
                                               int* __restrict__ cur1) {
    const int* deg = blockIdx.x ? deg1 : deg0;
    int* offs = blockIdx.x ? offs1 : offs0;
    int* cur = blockIdx.x ? cur1 : cur0;
    const int CH = (N_NODES + 1023) / 1024;   // 49
    int tid = threadIdx.x;
    int base = tid * CH;
    int sum = 0;
    for (int i = 0; i < CH; i++) {
        int idx = base + i;
        if (idx < N_NODES) sum += deg[idx];
    }
    __shared__ int ls[1024];
    ls[tid] = sum;
    __syncthreads();
    for (int ofs = 1; ofs < 1024; ofs <<= 1) {
        int v = (tid >= ofs) ? ls[tid - ofs] : 0;
        __syncthreads();
        ls[tid] += v;
        __syncthreads();
    }
    int prefix = (tid == 0) ? 0 : ls[tid - 1];
    for (int i = 0; i < CH; i++) {
        int idx = base + i;
        if (idx < N_NODES) {
            offs[idx] = prefix;
            cur[idx] = prefix;
            prefix += deg[idx];
        }
    }
}

// ---------------------------------------------------------------------------
// K_scatter: fill per-dst edge-id lists via cursor atomics
// ---------------------------------------------------------------------------
__global__ __launch_bounds__(256) void k_scatter(const int* __restrict__ dst0,
                                                 const int* __restrict__ dst1,
                                                 int* __restrict__ cur0,
                                                 int* __restrict__ cur1,
                                                 int* __restrict__ eid0,
                                                 int* __restrict__ eid1) {
    int e = blockIdx.x * 256 + threadIdx.x;
    if (e < N_EDGES) {
        int p0 = atomicAdd(&cur0[dst0[e]], 1);
        eid0[p0] = e;
        int p1 = atomicAdd(&cur1[dst1[e]], 1);
        eid1[p1] = e;
    }
}

// ---------------------------------------------------------------------------
// K1: fused GEMM  C[m, 0:384] = x[m,:] @ {fc_w0, fc_w1, skip_w}^T
// ---------------------------------------------------------------------------
__global__ __launch_bounds__(256) void k_gemm3(const float* __restrict__ x,
                                               const float* __restrict__ w0,
                                               const float* __restrict__ w1,
                                               const float* __restrict__ wsk,
                                               const float* __restrict__ skip_b,
                                               float* __restrict__ f0,
                                               float* __restrict__ f1,
                                               float* __restrict__ hs) {
    __shared__ float As[64][132];
    __shared__ float Bs[64][132];

    int tid = threadIdx.x;
    int m0 = blockIdx.y * 64;
    int jblk = blockIdx.x;                 // 0..5
    const float* W = (jblk < 2) ? w0 : (jblk < 4) ? w1 : wsk;
    int j0 = (jblk & 1) * 64;

    for (int i = 0; i < 8; i++) {
        int idx = tid * 8 + i;
        int row = idx >> 5;
        int c4 = idx & 31;
        float4 v = make_float4(0.f, 0.f, 0.f, 0.f);
        int gr = m0 + row;
        if (gr < N_NODES) v = *(const float4*)(x + (size_t)gr * HID + c4 * 4);
        *(float4*)(&As[row][c4 * 4]) = v;
        float4 wv = *(const float4*)(W + (size_t)(j0 + row) * HID + c4 * 4);
        *(float4*)(&Bs[row][c4 * 4]) = wv;
    }
    __syncthreads();

    int tx = tid & 15, ty = tid >> 4;
    float acc[4][4] = {};
    for (int k = 0; k < 128; k += 4) {
        float4 a[4], b[4];
#pragma unroll
        for (int i = 0; i < 4; i++) a[i] = *(const float4*)(&As[ty + 16 * i][k]);
#pragma unroll
        for (int j = 0; j < 4; j++) b[j] = *(const float4*)(&Bs[tx + 16 * j][k]);
#pragma unroll
        for (int i = 0; i < 4; i++)
#pragma unroll
            for (int j = 0; j < 4; j++)
                acc[i][j] += a[i].x * b[j].x + a[i].y * b[j].y +
                             a[i].z * b[j].z + a[i].w * b[j].w;
    }

    float* dstp = (jblk < 2) ? f0 : (jblk < 4) ? f1 : hs;
#pragma unroll
    for (int i = 0; i < 4; i++) {
        int gr = m0 + ty + 16 * i;
        if (gr >= N_NODES) continue;
#pragma unroll
        for (int j = 0; j < 4; j++) {
            int col = j0 + tx + 16 * j;
            float v = acc[i][j];
            if (jblk >= 4) v += skip_b[col];
            dstp[(size_t)gr * HID + col] = v;
        }
    }
}

// ---------------------------------------------------------------------------
// K1b: el/er = sum_d f[n,h,d] * attn_{l,r}[h,d]   (wave per (node,head))
// ---------------------------------------------------------------------------
__global__ __launch_bounds__(256) void k_attn_dots(const float* __restrict__ f0,
                                                   const float* __restrict__ f1,
                                                   const float* __restrict__ al0,
                                                   const float* __restrict__ ar0,
                                                   const float* __restrict__ al1,
                                                   const float* __restrict__ ar1,
                                                   float* __restrict__ el0,
                                                   float* __restrict__ er0,
                                                   float* __restrict__ el1,
                                                   float* __restrict__ er1) {
    int wave = threadIdx.x >> 6;
    int lane = threadIdx.x & 63;
    int n = blockIdx.x * 2 + (wave >> 1);
    int h = wave & 1;
    if (n >= N_NODES) return;
    int c = h * 64 + lane;
    float v0 = f0[(size_t)n * HID + c];
    float v1 = f1[(size_t)n * HID + c];
    float s0 = v0 * al0[c], s1 = v0 * ar0[c];
    float s2 = v1 * al1[c], s3 = v1 * ar1[c];
#pragma unroll
    for (int m = 32; m; m >>= 1) {
        s0 += __shfl_xor(s0, m);
        s1 += __shfl_xor(s1, m);
        s2 += __shfl_xor(s2, m);
        s3 += __shfl_xor(s3, m);
    }
    if (lane == 0) {
        el0[n * 2 + h] = s0;
        er0[n * 2 + h] = s1;
        el1[n * 2 + h] = s2;
        er1[n * 2 + h] = s3;
    }
}

// ---------------------------------------------------------------------------
// K_aggregate: wave per dst node. Two relations. Per relation:
//   pass A: den_h = sum over in-edges of exp(leaky(el[src]+er[n]))
//   pass B: acc += (ex/den * ew) * f[src]   (gather, register accumulate)
// Writes acc[n,:] = relu(bias0+bias1+sum0+sum1) exactly once. No atomics.
// ---------------------------------------------------------------------------
__device__ __forceinline__ void agg_rel(const int* __restrict__ src,
                                        const float* __restrict__ ew,
                                        const int* __restrict__ offs,
                                        const int* __restrict__ eid,
                                        const float* __restrict__ el,
                                        const float* __restrict__ er,
                                        const float* __restrict__ f,
                                        int n, int h, int c,
                                        float& a0, float& a1) {
    int b = offs[n];
    int e_end = (n == N_NODES - 1) ? N_EDGES : offs[n + 1];
    if (b == e_end) return;
    float ern = er[n * 2 + h];
    // pass A: denominator (all lanes of the half-wave compute the same value)
    float den = 0.f;
    int p = b;
    for (; p + 2 <= e_end; p += 2) {
        int ea = eid[p], eb = eid[p + 1];
        int sa = src[ea], sb = src[eb];
        den += expf(leaky(el[sa * 2 + h] + ern));
        den += expf(leaky(el[sb * 2 + h] + ern));
    }
    if (p < e_end) {
        int ea = eid[p];
        den += expf(leaky(el[src[ea] * 2 + h] + ern));
    }
    float inv = 1.f / den;
    // pass B: weighted gather-accumulate
    p = b;
    for (; p + 2 <= e_end; p += 2) {
        int ea = eid[p], eb = eid[p + 1];
        int sa = src[ea], sb = src[eb];
        float2 fa = *(const float2*)(f + (size_t)sa * HID + c);
        float2 fb = *(const float2*)(f + (size_t)sb * HID + c);
        float aa = expf(leaky(el[sa * 2 + h] + ern)) * inv * ew[ea];
        float ab = expf(leaky(el[sb * 2 + h] + ern)) * inv * ew[eb];
        a0 += aa * fa.x + ab * fb.x;
        a1 += aa * fa.y + ab * fb.y;
    }
    if (p < e_end) {
        int ea = eid[p];
        int sa = src[ea];
        float2 fa = *(const float2*)(f + (size_t)sa * HID + c);
        float aa = expf(leaky(el[sa * 2 + h] + ern)) * inv * ew[ea];
        a0 += aa * fa.x;
        a1 += aa * fa.y;
    }
}

__global__ __launch_bounds__(256) void k_aggregate(
    const int* __restrict__ src0, const float* __restrict__ ew0,
    const int* __restrict__ offs0, const int* __restrict__ eid0,
    const float* __restrict__ el0, const float* __restrict__ er0,
    const float* __restrict__ f0,
    const int* __restrict__ src1, const float* __restrict__ ew1,
    const int* __restrict__ offs1, const int* __restrict__ eid1,
    const float* __restrict__ el1, const float* __restrict__ er1,
    const float* __restrict__ f1,
    const float* __restrict__ bias0, const float* __restrict__ bias1,
    float* __restrict__ acc) {
    int wave = threadIdx.x >> 6, lane = threadIdx.x & 63;
    int n = blockIdx.x * 4 + wave;
    if (n >= N_NODES) return;
    int h = lane >> 5;       // head of this lane's columns
    int c = lane * 2;        // columns c, c+1
    float a0 = bias0[c] + bias1[c];
    float a1 = bias0[c + 1] + bias1[c + 1];
    agg_rel(src0, ew0, offs0, eid0, el0, er0, f0, n, h, c, a0, a1);
    agg_rel(src1, ew1, offs1, eid1, el1, er1, f1, n, h, c, a0, a1);
    float2 o = make_float2(fmaxf(a0, 0.f), fmaxf(a1, 0.f));   // relu folded
    *(float2*)(acc + (size_t)n * HID + c) = o;
}

// ---------------------------------------------------------------------------
// K4: h = hs + acc (acc already relu'd); per-column partial sums (double)
//     Launch with EXACTLY 512 blocks x 256 threads.
// ---------------------------------------------------------------------------
__global__ __launch_bounds__(256) void k_h_bn(float* __restrict__ h,
                                              const float* __restrict__ acc,
                                              double* __restrict__ psum,
                                              double* __restrict__ psumsq) {
    int tid = threadIdx.x;
    double s = 0.0, q = 0.0;
    const int total = N_NODES * HID;
    const int stride = 512 * 256;
    for (int idx = blockIdx.x * 256 + tid; idx < total; idx += stride) {
        float v = h[idx] + acc[idx];
        h[idx] = v;
        s += v;
        q += (double)v * v;
    }
    __shared__ double ls[256], lq[256];
    ls[tid] = s;
    lq[tid] = q;
    __syncthreads();
    if (tid < 128) {
        psum[blockIdx.x * 128 + tid] = ls[tid] + ls[tid + 128];
        psumsq[blockIdx.x * 128 + tid] = lq[tid] + lq[tid + 128];
    }
}

// ---------------------------------------------------------------------------
// K5: finalize BN scale/shift per column. 1 block x 128 threads.
// ---------------------------------------------------------------------------
__global__ void k_bn_finalize(const double* __restrict__ psum,
                              const double* __restrict__ psumsq,
                              const float* __restrict__ gamma,
                              const float* __restrict__ beta,
                              float* __restrict__ ss) {
    int c = threadIdx.x;
    double s = 0.0, q = 0.0;
    for (int b = 0; b < 512; b++) {
        s += psum[b * 128 + c];
        q += psumsq[b * 128 + c];
    }
    double mu = s / N_NODES;
    double var = q / N_NODES - mu * mu;
    float sc = gamma[c] * (float)(1.0 / sqrt(var + (double)BN_EPS));
    ss[c] = sc;
    ss[128 + c] = beta[c] - (float)mu * sc;
}

// ---------------------------------------------------------------------------
// K6: logits[n,k] = relu(h*scale+shift) . clf_w[k,:] + clf_b[k]
// ---------------------------------------------------------------------------
__global__ __launch_bounds__(256) void k_classify(const float* __restrict__ h,
                                                  const float* __restrict__ ss,
                                                  const float* __restrict__ clf_w,
                                                  const float* __restrict__ clf_b,
                                                  float* __restrict__ out) {
    int wave = threadIdx.x >> 6, lane = threadIdx.x & 63;
    int n = blockIdx.x * 4 + wave;
    if (n >= N_NODES) return;
    float v0 = h[(size_t)n * HID + lane] * ss[lane] + ss[128 + lane];
    float v1 = h[(size_t)n * HID + 64 + lane] * ss[64 + lane] + ss[192 + lane];
    v0 = fmaxf(v0, 0.f);
    v1 = fmaxf(v1, 0.f);
#pragma unroll
    for (int k = 0; k < 16; k++) {
        float p = v0 * clf_w[k * 128 + lane] + v1 * clf_w[k * 128 + 64 + lane];
#pragma unroll
        for (int m = 32; m; m >>= 1) p += __shfl_xor(p, m);
        if (lane == 0) out[(size_t)n * 16 + k] = p + clf_b[k];
    }
}

// ---------------------------------------------------------------------------
extern "C" void kernel_launch(void* const* d_in, const int* in_sizes, int n_in,
                              void* d_out, int out_size, void* d_ws, size_t ws_size,
                              hipStream_t stream) {
    (void)in_sizes; (void)n_in; (void)out_size; (void)ws_size;
    const float* x      = (const float*)d_in[0];
    const int*   src0   = (const int*)d_in[1];
    const int*   dst0   = (const int*)d_in[2];
    const float* ew0    = (const float*)d_in[3];
    const int*   src1   = (const int*)d_in[4];
    const int*   dst1   = (const int*)d_in[5];
    const float* ew1    = (const float*)d_in[6];
    const float* fc_w0  = (const float*)d_in[7];
    const float* bias0  = (const float*)d_in[8];
    const float* al0    = (const float*)d_in[9];
    const float* ar0    = (const float*)d_in[10];
    const float* fc_w1  = (const float*)d_in[11];
    const float* bias1  = (const float*)d_in[12];
    const float* al1    = (const float*)d_in[13];
    const float* ar1    = (const float*)d_in[14];
    const float* skip_w = (const float*)d_in[15];
    const float* skip_b = (const float*)d_in[16];
    const float* gamma  = (const float*)d_in[17];
    const float* beta   = (const float*)d_in[18];
    const float* clf_w  = (const float*)d_in[19];
    const float* clf_b  = (const float*)d_in[20];
    float* out = (float*)d_out;

    char* wsp = (char*)d_ws;
    size_t off = 0;
    auto alloc = [&](size_t bytes) -> char* {
        char* p = wsp + off;
        off += (bytes + 255) & ~(size_t)255;
        return p;
    };
    float*  f0     = (float*)alloc((size_t)N_NODES * HID * 4);
    float*  f1     = (float*)alloc((size_t)N_NODES * HID * 4);
    float*  hs     = (float*)alloc((size_t)N_NODES * HID * 4);   // becomes h
    float*  acc    = (float*)alloc((size_t)N_NODES * HID * 4);
    float*  el0    = (float*)alloc((size_t)N_NODES * 2 * 4);
    float*  er0    = (float*)alloc((size_t)N_NODES * 2 * 4);
    float*  el1    = (float*)alloc((size_t)N_NODES * 2 * 4);
    float*  er1    = (float*)alloc((size_t)N_NODES * 2 * 4);
    int*    deg0   = (int*)alloc((size_t)N_NODES * 4);
    int*    deg1   = (int*)alloc((size_t)N_NODES * 4);
    int*    offs0  = (int*)alloc((size_t)N_NODES * 4);
    int*    offs1  = (int*)alloc((size_t)N_NODES * 4);
    int*    cur0   = (int*)alloc((size_t)N_NODES * 4);
    int*    cur1   = (int*)alloc((size_t)N_NODES * 4);
    int*    eid0   = (int*)alloc((size_t)N_EDGES * 4);
    int*    eid1   = (int*)alloc((size_t)N_EDGES * 4);
    double* psum   = (double*)alloc((size_t)512 * 128 * 8);
    double* psumsq = (double*)alloc((size_t)512 * 128 * 8);
    float*  ss     = (float*)alloc(256 * 4);

    int gN = (N_NODES + 255) / 256;
    int gE = (N_EDGES + 255) / 256;

    // CSR build (independent of GEMM)
    k_zero<<<gN, 256, 0, stream>>>(deg0, deg1);
    k_count<<<gE, 256, 0, stream>>>(dst0, dst1, deg0, deg1);
    k_scan<<<2, 1024, 0, stream>>>(deg0, deg1, offs0, offs1, cur0, cur1);
    k_scatter<<<gE, 256, 0, stream>>>(dst0, dst1, cur0, cur1, eid0, eid1);

    // node features
    dim3 g1(6, (N_NODES + 63) / 64);
    k_gemm3<<<g1, 256, 0, stream>>>(x, fc_w0, fc_w1, skip_w, skip_b, f0, f1, hs);
    k_attn_dots<<<(N_NODES + 1) / 2, 256, 0, stream>>>(f0, f1, al0, ar0, al1, ar1,
                                                       el0, er0, el1, er1);

    // gather-based aggregation (no atomics)
    k_aggregate<<<(N_NODES + 3) / 4, 256, 0, stream>>>(
        src0, ew0, offs0, eid0, el0, er0, f0,
        src1, ew1, offs1, eid1, el1, er1, f1,
        bias0, bias1, acc);

    k_h_bn<<<512, 256, 0, stream>>>(hs, acc, psum, psumsq);
    k_bn_finalize<<<1, 128, 0, stream>>>(psum, psumsq, gamma, beta, ss);
    k_classify<<<(N_NODES + 3) / 4, 256, 0, stream>>>(hs, ss, clf_w, clf_b, out);
}

// Round 3
// 668.300 us; speedup vs baseline: 1.5401x; 1.2545x over previous
//
#include <hip/hip_runtime.h>
#include <hip/hip_bf16.h>

// Problem constants (match reference)
#define N_NODES 50000
#define N_EDGES 800000
#define HID 128          // HEADS*HEAD_DIM
#define NEG_SLOPE 0.2f
#define BN_EPS 1e-5f

__device__ __forceinline__ float leaky(float v) {
    return (v > 0.f) ? v : v * NEG_SLOPE;
}

// ---------------------------------------------------------------------------
// CSR build: zero -> count -> scan -> scatter
// ---------------------------------------------------------------------------
__global__ __launch_bounds__(256) void k_zero(int* __restrict__ deg0,
                                              int* __restrict__ deg1) {
    int i = blockIdx.x * 256 + threadIdx.x;
    if (i < N_NODES) {
        deg0[i] = 0;
        deg1[i] = 0;
    }
}

__global__ __launch_bounds__(256) void k_count(const int* __restrict__ dst0,
                                               const int* __restrict__ dst1,
                                               int* __restrict__ deg0,
                                               int* __restrict__ deg1) {
    int e = blockIdx.x * 256 + threadIdx.x;
    if (e < N_EDGES) {
        atomicAdd(&deg0[dst0[e]], 1);
        atomicAdd(&deg1[dst1[e]], 1);
    }
}

__global__ __launch_bounds__(1024) void k_scan(const int* __restrict__ deg0,
                                               const int* __restrict__ deg1,
                                               int* __restrict__ offs0,
                                               int* __restrict__ offs1,
                                               int* __restrict__ cur0,
                                               int* __restrict__ cur1) {
    const int* deg = blockIdx.x ? deg1 : deg0;
    int* offs = blockIdx.x ? offs1 : offs0;
    int* cur = blockIdx.x ? cur1 : cur0;
    const int CH = (N_NODES + 1023) / 1024;   // 49
    int tid = threadIdx.x;
    int base = tid * CH;
    int sum = 0;
    for (int i = 0; i < CH; i++) {
        int idx = base + i;
        if (idx < N_NODES) sum += deg[idx];
    }
    __shared__ int ls[1024];
    ls[tid] = sum;
    __syncthreads();
    for (int ofs = 1; ofs < 1024; ofs <<= 1) {
        int v = (tid >= ofs) ? ls[tid - ofs] : 0;
        __syncthreads();
        ls[tid] += v;
        __syncthreads();
    }
    int prefix = (tid == 0) ? 0 : ls[tid - 1];
    for (int i = 0; i < CH; i++) {
        int idx = base + i;
        if (idx < N_NODES) {
            offs[idx] = prefix;
            cur[idx] = prefix;
            prefix += deg[idx];
        }
    }
}

__global__ __launch_bounds__(256) void k_scatter(const int* __restrict__ dst0,
                                                 const int* __restrict__ dst1,
                                                 int* __restrict__ cur0,
                                                 int* __restrict__ cur1,
                                                 int* __restrict__ eid0,
                                                 int* __restrict__ eid1) {
    int e = blockIdx.x * 256 + threadIdx.x;
    if (e < N_EDGES) {
        int p0 = atomicAdd(&cur0[dst0[e]], 1);
        eid0[p0] = e;
        int p1 = atomicAdd(&cur1[dst1[e]], 1);
        eid1[p1] = e;
    }
}

// ---------------------------------------------------------------------------
// K1: fused GEMM  [m, 0:384] = x[m,:] @ {fc_w0, fc_w1, skip_w}^T
//     jblk 0..3: writes bf16 f-tables + fused el/er attention dots
//     jblk 4..5: writes f32 hs (+skip_b)
// ---------------------------------------------------------------------------
__global__ __launch_bounds__(256) void k_gemm3(
    const float* __restrict__ x,
    const float* __restrict__ w0, const float* __restrict__ w1,
    const float* __restrict__ wsk, const float* __restrict__ skip_b,
    const float* __restrict__ al0, const float* __restrict__ ar0,
    const float* __restrict__ al1, const float* __restrict__ ar1,
    __hip_bfloat16* __restrict__ fb0, __hip_bfloat16* __restrict__ fb1,
    float* __restrict__ el0, float* __restrict__ er0,
    float* __restrict__ el1, float* __restrict__ er1,
    float* __restrict__ hs) {
    __shared__ float As[64][132];
    __shared__ float Bs[64][132];

    int tid = threadIdx.x;
    int m0 = blockIdx.y * 64;
    int jblk = blockIdx.x;                 // 0..5
    const float* W = (jblk < 2) ? w0 : (jblk < 4) ? w1 : wsk;
    int j0 = (jblk & 1) * 64;

    for (int i = 0; i < 8; i++) {
        int idx = tid * 8 + i;
        int row = idx >> 5;
        int c4 = idx & 31;
        float4 v = make_float4(0.f, 0.f, 0.f, 0.f);
        int gr = m0 + row;
        if (gr < N_NODES) v = *(const float4*)(x + (size_t)gr * HID + c4 * 4);
        *(float4*)(&As[row][c4 * 4]) = v;
        float4 wv = *(const float4*)(W + (size_t)(j0 + row) * HID + c4 * 4);
        *(float4*)(&Bs[row][c4 * 4]) = wv;
    }
    __syncthreads();

    int tx = tid & 15, ty = tid >> 4;
    float acc[4][4] = {};
    for (int k = 0; k < 128; k += 4) {
        float4 a[4], b[4];
#pragma unroll
        for (int i = 0; i < 4; i++) a[i] = *(const float4*)(&As[ty + 16 * i][k]);
#pragma unroll
        for (int j = 0; j < 4; j++) b[j] = *(const float4*)(&Bs[tx + 16 * j][k]);
#pragma unroll
        for (int i = 0; i < 4; i++)
#pragma unroll
            for (int j = 0; j < 4; j++)
                acc[i][j] += a[i].x * b[j].x + a[i].y * b[j].y +
                             a[i].z * b[j].z + a[i].w * b[j].w;
    }

    if (jblk < 4) {
        int rel = jblk >> 1;
        int h = jblk & 1;
        const float* al = rel ? al1 : al0;
        const float* ar = rel ? ar1 : ar0;
        float* elp = rel ? el1 : el0;
        float* erp = rel ? er1 : er0;
        __hip_bfloat16* fb = rel ? fb1 : fb0;

        // fused attention dots: per-thread partials over its 4 cols
        float elv[4] = {0.f, 0.f, 0.f, 0.f};
        float erv[4] = {0.f, 0.f, 0.f, 0.f};
#pragma unroll
        for (int j = 0; j < 4; j++) {
            int col = j0 + tx + 16 * j;
            float av = al[col], rv = ar[col];
#pragma unroll
            for (int i = 0; i < 4; i++) {
                elv[i] += acc[i][j] * av;
                erv[i] += acc[i][j] * rv;
            }
        }
        // reduce across the 16 threads (tx) sharing each row
#pragma unroll
        for (int m = 1; m < 16; m <<= 1) {
#pragma unroll
            for (int i = 0; i < 4; i++) {
                elv[i] += __shfl_xor(elv[i], m);
                erv[i] += __shfl_xor(erv[i], m);
            }
        }
        // bf16 f-table stores
#pragma unroll
        for (int i = 0; i < 4; i++) {
            int gr = m0 + ty + 16 * i;
            if (gr >= N_NODES) continue;
#pragma unroll
            for (int j = 0; j < 4; j++) {
                int col = j0 + tx + 16 * j;
                fb[(size_t)gr * HID + col] = __float2bfloat16(acc[i][j]);
            }
            if (tx == 0) {
                elp[gr * 2 + h] = elv[i];
                erp[gr * 2 + h] = erv[i];
            }
        }
    } else {
#pragma unroll
        for (int i = 0; i < 4; i++) {
            int gr = m0 + ty + 16 * i;
            if (gr >= N_NODES) continue;
#pragma unroll
            for (int j = 0; j < 4; j++) {
                int col = j0 + tx + 16 * j;
                hs[(size_t)gr * HID + col] = acc[i][j] + skip_b[col];
            }
        }
    }
}

// ---------------------------------------------------------------------------
// K_aggregate: wave per dst node; lane-parallel softmax, readlane broadcast,
//              bf16 f gather. No atomics.
// ---------------------------------------------------------------------------
__device__ __forceinline__ void agg_rel(const int* __restrict__ src,
                                        const float* __restrict__ ew,
                                        const int* __restrict__ offs,
                                        const int* __restrict__ eid,
                                        const float* __restrict__ el,
                                        const float* __restrict__ er,
                                        const __hip_bfloat16* __restrict__ fb,
                                        int n, int lane, int c, float invsel_h,
                                        float& a0, float& a1, int h) {
    int b = offs[n];
    int e_end = (n == N_NODES - 1) ? N_EDGES : offs[n + 1];
    int deg = e_end - b;
    if (deg <= 0) return;
    float ern0 = er[2 * n], ern1 = er[2 * n + 1];

    const int NC = 4;                       // cached chunks (256 edges)
    int cs[NC];
    float cw0[NC], cw1[NC];
    float d0 = 0.f, d1 = 0.f;
    int nchunk = (deg + 63) >> 6;
    for (int ch = 0; ch < nchunk; ch++) {
        int p = b + (ch << 6) + lane;
        int s = 0;
        float w0 = 0.f, w1 = 0.f;
        if (p < e_end) {
            int e = eid[p];
            s = src[e];
            float2 elv = *(const float2*)(el + 2 * s);
            float wgt = ew[e];
            float x0 = expf(leaky(elv.x + ern0));
            float x1 = expf(leaky(elv.y + ern1));
            d0 += x0;
            d1 += x1;
            w0 = x0 * wgt;
            w1 = x1 * wgt;
        }
        if (ch < NC) {
            cs[ch] = s;
            cw0[ch] = w0;
            cw1[ch] = w1;
        }
    }
#pragma unroll
    for (int m = 32; m; m >>= 1) {
        d0 += __shfl_xor(d0, m);
        d1 += __shfl_xor(d1, m);
    }
    float inv0 = 1.f / d0, inv1 = 1.f / d1;
    float invh = h ? inv1 : inv0;

    for (int ch = 0; ch < nchunk; ch++) {
        int cnt = deg - (ch << 6);
        if (cnt > 64) cnt = 64;
        int s;
        float w0, w1;
        if (ch < NC) {
            s = cs[ch];
            w0 = cw0[ch];
            w1 = cw1[ch];
        } else {                              // rare: recompute
            int p = b + (ch << 6) + lane;
            s = 0; w0 = 0.f; w1 = 0.f;
            if (p < e_end) {
                int e = eid[p];
                s = src[e];
                float2 elv = *(const float2*)(el + 2 * s);
                float wgt = ew[e];
                w0 = expf(leaky(elv.x + ern0)) * wgt;
                w1 = expf(leaky(elv.y + ern1)) * wgt;
            }
        }
        for (int j = 0; j < cnt; j++) {
            int sj = __shfl(s, j);
            float w0j = __shfl(w0, j);
            float w1j = __shfl(w1, j);
            float aj = (h ? w1j : w0j) * invh;
            __hip_bfloat162 fv =
                *(const __hip_bfloat162*)(fb + (size_t)sj * HID + c);
            a0 += aj * __bfloat162float(fv.x);
            a1 += aj * __bfloat162float(fv.y);
        }
    }
    (void)invsel_h;
}

__global__ __launch_bounds__(256) void k_aggregate(
    const int* __restrict__ src0, const float* __restrict__ ew0,
    const int* __restrict__ offs0, const int* __restrict__ eid0,
    const float* __restrict__ el0, const float* __restrict__ er0,
    const __hip_bfloat16* __restrict__ fb0,
    const int* __restrict__ src1, const float* __restrict__ ew1,
    const int* __restrict__ offs1, const int* __restrict__ eid1,
    const float* __restrict__ el1, const float* __restrict__ er1,
    const __hip_bfloat16* __restrict__ fb1,
    const float* __restrict__ bias0, const float* __restrict__ bias1,
    float* __restrict__ acc) {
    int wave = threadIdx.x >> 6, lane = threadIdx.x & 63;
    int n = blockIdx.x * 4 + wave;
    if (n >= N_NODES) return;
    int h = lane >> 5;
    int c = lane * 2;
    float a0 = bias0[c] + bias1[c];
    float a1 = bias0[c + 1] + bias1[c + 1];
    agg_rel(src0, ew0, offs0, eid0, el0, er0, fb0, n, lane, c, 0.f, a0, a1, h);
    agg_rel(src1, ew1, offs1, eid1, el1, er1, fb1, n, lane, c, 0.f, a0, a1, h);
    float2 o = make_float2(fmaxf(a0, 0.f), fmaxf(a1, 0.f));   // relu folded
    *(float2*)(acc + (size_t)n * HID + c) = o;
}

// ---------------------------------------------------------------------------
// K4: h = hs + acc (acc already relu'd); per-column partial sums (double)
//     Launch with EXACTLY 512 blocks x 256 threads.
// ---------------------------------------------------------------------------
__global__ __launch_bounds__(256) void k_h_bn(float* __restrict__ h,
                                              const float* __restrict__ acc,
                                              double* __restrict__ psum,
                                              double* __restrict__ psumsq) {
    int tid = threadIdx.x;
    double s = 0.0, q = 0.0;
    const int total = N_NODES * HID;
    const int stride = 512 * 256;
    for (int idx = blockIdx.x * 256 + tid; idx < total; idx += stride) {
        float v = h[idx] + acc[idx];
        h[idx] = v;
        s += v;
        q += (double)v * v;
    }
    __shared__ double ls[256], lq[256];
    ls[tid] = s;
    lq[tid] = q;
    __syncthreads();
    if (tid < 128) {
        psum[blockIdx.x * 128 + tid] = ls[tid] + ls[tid + 128];
        psumsq[blockIdx.x * 128 + tid] = lq[tid] + lq[tid + 128];
    }
}

__global__ void k_bn_finalize(const double* __restrict__ psum,
                              const double* __restrict__ psumsq,
                              const float* __restrict__ gamma,
                              const float* __restrict__ beta,
                              float* __restrict__ ss) {
    int c = threadIdx.x;
    double s = 0.0, q = 0.0;
    for (int b = 0; b < 512; b++) {
        s += psum[b * 128 + c];
        q += psumsq[b * 128 + c];
    }
    double mu = s / N_NODES;
    double var = q / N_NODES - mu * mu;
    float sc = gamma[c] * (float)(1.0 / sqrt(var + (double)BN_EPS));
    ss[c] = sc;
    ss[128 + c] = beta[c] - (float)mu * sc;
}

__global__ __launch_bounds__(256) void k_classify(const float* __restrict__ h,
                                                  const float* __restrict__ ss,
                                                  const float* __restrict__ clf_w,
                                                  const float* __restrict__ clf_b,
                                                  float* __restrict__ out) {
    int wave = threadIdx.x >> 6, lane = threadIdx.x & 63;
    int n = blockIdx.x * 4 + wave;
    if (n >= N_NODES) return;
    float v0 = h[(size_t)n * HID + lane] * ss[lane] + ss[128 + lane];
    float v1 = h[(size_t)n * HID + 64 + lane] * ss[64 + lane] + ss[192 + lane];
    v0 = fmaxf(v0, 0.f);
    v1 = fmaxf(v1, 0.f);
#pragma unroll
    for (int k = 0; k < 16; k++) {
        float p = v0 * clf_w[k * 128 + lane] + v1 * clf_w[k * 128 + 64 + lane];
#pragma unroll
        for (int m = 32; m; m >>= 1) p += __shfl_xor(p, m);
        if (lane == 0) out[(size_t)n * 16 + k] = p + clf_b[k];
    }
}

// ---------------------------------------------------------------------------
extern "C" void kernel_launch(void* const* d_in, const int* in_sizes, int n_in,
                              void* d_out, int out_size, void* d_ws, size_t ws_size,
                              hipStream_t stream) {
    (void)in_sizes; (void)n_in; (void)out_size; (void)ws_size;
    const float* x      = (const float*)d_in[0];
    const int*   src0   = (const int*)d_in[1];
    const int*   dst0   = (const int*)d_in[2];
    const float* ew0    = (const float*)d_in[3];
    const int*   src1   = (const int*)d_in[4];
    const int*   dst1   = (const int*)d_in[5];
    const float* ew1    = (const float*)d_in[6];
    const float* fc_w0  = (const float*)d_in[7];
    const float* bias0  = (const float*)d_in[8];
    const float* al0    = (const float*)d_in[9];
    const float* ar0    = (const float*)d_in[10];
    const float* fc_w1  = (const float*)d_in[11];
    const float* bias1  = (const float*)d_in[12];
    const float* al1    = (const float*)d_in[13];
    const float* ar1    = (const float*)d_in[14];
    const float* skip_w = (const float*)d_in[15];
    const float* skip_b = (const float*)d_in[16];
    const float* gamma  = (const float*)d_in[17];
    const float* beta   = (const float*)d_in[18];
    const float* clf_w  = (const float*)d_in[19];
    const float* clf_b  = (const float*)d_in[20];
    float* out = (float*)d_out;

    char* wsp = (char*)d_ws;
    size_t off = 0;
    auto alloc = [&](size_t bytes) -> char* {
        char* p = wsp + off;
        off += (bytes + 255) & ~(size_t)255;
        return p;
    };
    __hip_bfloat16* fb0 = (__hip_bfloat16*)alloc((size_t)N_NODES * HID * 2);
    __hip_bfloat16* fb1 = (__hip_bfloat16*)alloc((size_t)N_NODES * HID * 2);
    float*  hs     = (float*)alloc((size_t)N_NODES * HID * 4);   // becomes h
    float*  acc    = (float*)alloc((size_t)N_NODES * HID * 4);
    float*  el0    = (float*)alloc((size_t)N_NODES * 2 * 4);
    float*  er0    = (float*)alloc((size_t)N_NODES * 2 * 4);
    float*  el1    = (float*)alloc((size_t)N_NODES * 2 * 4);
    float*  er1    = (float*)alloc((size_t)N_NODES * 2 * 4);
    int*    deg0   = (int*)alloc((size_t)N_NODES * 4);
    int*    deg1   = (int*)alloc((size_t)N_NODES * 4);
    int*    offs0  = (int*)alloc((size_t)N_NODES * 4);
    int*    offs1  = (int*)alloc((size_t)N_NODES * 4);
    int*    cur0   = (int*)alloc((size_t)N_NODES * 4);
    int*    cur1   = (int*)alloc((size_t)N_NODES * 4);
    int*    eid0   = (int*)alloc((size_t)N_EDGES * 4);
    int*    eid1   = (int*)alloc((size_t)N_EDGES * 4);
    double* psum   = (double*)alloc((size_t)512 * 128 * 8);
    double* psumsq = (double*)alloc((size_t)512 * 128 * 8);
    float*  ss     = (float*)alloc(256 * 4);

    int gN = (N_NODES + 255) / 256;
    int gE = (N_EDGES + 255) / 256;

    // CSR build (independent of GEMM)
    k_zero<<<gN, 256, 0, stream>>>(deg0, deg1);
    k_count<<<gE, 256, 0, stream>>>(dst0, dst1, deg0, deg1);
    k_scan<<<2, 1024, 0, stream>>>(deg0, deg1, offs0, offs1, cur0, cur1);
    k_scatter<<<gE, 256, 0, stream>>>(dst0, dst1, cur0, cur1, eid0, eid1);

    // node features + fused attention dots + bf16 tables
    dim3 g1(6, (N_NODES + 63) / 64);
    k_gemm3<<<g1, 256, 0, stream>>>(x, fc_w0, fc_w1, skip_w, skip_b,
                                    al0, ar0, al1, ar1,
                                    fb0, fb1, el0, er0, el1, er1, hs);

    // gather-based aggregation (no atomics)
    k_aggregate<<<(N_NODES + 3) / 4, 256, 0, stream>>>(
        src0, ew0, offs0, eid0, el0, er0, fb0,
        src1, ew1, offs1, eid1, el1, er1, fb1,
        bias0, bias1, acc);

    k_h_bn<<<512, 256, 0, stream>>>(hs, acc, psum, psumsq);
    k_bn_finalize<<<1, 128, 0, stream>>>(psum, psumsq, gamma, beta, ss);
    k_classify<<<(N_NODES + 3) / 4, 256, 0, stream>>>(hs, ss, clf_w, clf_b, out);
}

// Round 4
// 409.006 us; speedup vs baseline: 2.5165x; 1.6340x over previous
//
#include <hip/hip_runtime.h>
#include <hip/hip_bf16.h>

// Problem constants (match reference)
#define N_NODES 50000
#define N_EDGES 800000
#define HID 128          // HEADS*HEAD_DIM
#define NEG_SLOPE 0.2f
#define BN_EPS 1e-5f

// CSR binning parameters
#define NBLK 256         // blocks over edges
#define BINSZ 1024       // nodes per bin (power of 2)
#define NBINS 49         // ceil(N_NODES / BINSZ)

__device__ __forceinline__ float leaky(float v) {
    return (v > 0.f) ? v : v * NEG_SLOPE;
}

// ---------------------------------------------------------------------------
// CSR build, pass A: per-block LDS histogram of dst bins (no global atomics)
// grid: (NBLK, 2)
// ---------------------------------------------------------------------------
__global__ __launch_bounds__(256) void k_bincount(const int* __restrict__ dst0,
                                                  const int* __restrict__ dst1,
                                                  int* __restrict__ bincnt) {
    int rel = blockIdx.y;
    const int* dst = rel ? dst1 : dst0;
    __shared__ int cnt[NBINS];
    for (int i = threadIdx.x; i < NBINS; i += 256) cnt[i] = 0;
    __syncthreads();
    const int CH = (N_EDGES + NBLK - 1) / NBLK;   // 3125
    int b0 = blockIdx.x * CH;
    int b1 = min(N_EDGES, b0 + CH);
    for (int e = b0 + threadIdx.x; e < b1; e += 256)
        atomicAdd(&cnt[dst[e] >> 10], 1);
    __syncthreads();
    for (int i = threadIdx.x; i < NBINS; i += 256)
        bincnt[rel * NBINS * NBLK + i * NBLK + blockIdx.x] = cnt[i];
}

// ---------------------------------------------------------------------------
// CSR pass B: in-place exclusive scan of bincnt per relation. grid: (2)
// ---------------------------------------------------------------------------
__global__ __launch_bounds__(1024) void k_binscan(int* __restrict__ bincnt) {
    int* a = bincnt + blockIdx.x * NBINS * NBLK;
    const int TOT = NBINS * NBLK;                 // 12544
    const int CH = (TOT + 1023) / 1024;           // 13
    int tid = threadIdx.x;
    int base = tid * CH;
    int lv[CH];
    int sum = 0;
    for (int i = 0; i < CH; i++) {
        int idx = base + i;
        int v = (idx < TOT) ? a[idx] : 0;
        lv[i] = sum;                              // thread-local exclusive
        sum += v;
    }
    __shared__ int ls[1024];
    ls[tid] = sum;
    __syncthreads();
    for (int ofs = 1; ofs < 1024; ofs <<= 1) {
        int v = (tid >= ofs) ? ls[tid - ofs] : 0;
        __syncthreads();
        ls[tid] += v;
        __syncthreads();
    }
    int pre = tid ? ls[tid - 1] : 0;
    for (int i = 0; i < CH; i++) {
        int idx = base + i;
        if (idx < TOT) a[idx] = pre + lv[i];
    }
}

// ---------------------------------------------------------------------------
// CSR pass C: scatter (dst,eid) pairs into per-(bin,block) contiguous runs.
// grid: (NBLK, 2). Writes are dense runs -> full-line, block-exclusive.
// ---------------------------------------------------------------------------
__global__ __launch_bounds__(256) void k_binscatter(const int* __restrict__ dst0,
                                                    const int* __restrict__ dst1,
                                                    const int* __restrict__ bincnt,
                                                    int2* __restrict__ pairs0,
                                                    int2* __restrict__ pairs1) {
    int rel = blockIdx.y;
    const int* dst = rel ? dst1 : dst0;
    int2* pairs = rel ? pairs1 : pairs0;
    __shared__ int cur[NBINS];
    for (int i = threadIdx.x; i < NBINS; i += 256)
        cur[i] = bincnt[rel * NBINS * NBLK + i * NBLK + blockIdx.x];
    __syncthreads();
    const int CH = (N_EDGES + NBLK - 1) / NBLK;
    int b0 = blockIdx.x * CH;
    int b1 = min(N_EDGES, b0 + CH);
    for (int e = b0 + threadIdx.x; e < b1; e += 256) {
        int d = dst[e];
        int pos = atomicAdd(&cur[d >> 10], 1);
        pairs[pos] = make_int2(d, e);
    }
}

// ---------------------------------------------------------------------------
// CSR pass D: per (rel,bin): LDS node histogram -> LDS scan -> offs (+sentinel)
// -> place eids within the bin's contiguous block-exclusive window.
// grid: (NBINS, 2)
// ---------------------------------------------------------------------------
__global__ __launch_bounds__(256) void k_csr(const int* __restrict__ bincnt,
                                             const int2* __restrict__ pairs0,
                                             const int2* __restrict__ pairs1,
                                             int* __restrict__ offs0,
                                             int* __restrict__ offs1,
                                             int* __restrict__ eid0,
                                             int* __restrict__ eid1) {
    int rel = blockIdx.y;
    const int2* pairs = rel ? pairs1 : pairs0;
    int* offs = rel ? offs1 : offs0;
    int* eid = rel ? eid1 : eid0;
    int bin = blockIdx.x;
    int tid = threadIdx.x;
    const int* bc = bincnt + rel * NBINS * NBLK;
    int pbase = bc[bin * NBLK];
    int pend = (bin < NBINS - 1) ? bc[(bin + 1) * NBLK] : N_EDGES;
    int n0 = bin << 10;
    int nn = min(N_NODES - n0, BINSZ);

    __shared__ int s_deg[BINSZ];
    __shared__ int s_ts[256];
    for (int i = tid; i < BINSZ; i += 256) s_deg[i] = 0;
    __syncthreads();
    for (int p = pbase + tid; p < pend; p += 256)
        atomicAdd(&s_deg[pairs[p].x - n0], 1);
    __syncthreads();

    // 256-thread exclusive scan over 1024 (4 per thread; own-slot access only)
    int d0 = s_deg[tid * 4], d1 = s_deg[tid * 4 + 1];
    int d2 = s_deg[tid * 4 + 2], d3 = s_deg[tid * 4 + 3];
    s_ts[tid] = d0 + d1 + d2 + d3;
    __syncthreads();
    for (int ofs = 1; ofs < 256; ofs <<= 1) {
        int v = (tid >= ofs) ? s_ts[tid - ofs] : 0;
        __syncthreads();
        s_ts[tid] += v;
        __syncthreads();
    }
    int pre = tid ? s_ts[tid - 1] : 0;
    s_deg[tid * 4] = pbase + pre;
    s_deg[tid * 4 + 1] = pbase + pre + d0;
    s_deg[tid * 4 + 2] = pbase + pre + d0 + d1;
    s_deg[tid * 4 + 3] = pbase + pre + d0 + d1 + d2;
    __syncthreads();

    for (int l = tid; l < nn; l += 256) offs[n0 + l] = s_deg[l];
    if (bin == NBINS - 1 && tid == 0) offs[N_NODES] = N_EDGES;
    __syncthreads();

    for (int p = pbase + tid; p < pend; p += 256) {
        int2 pr = pairs[p];
        int pos = atomicAdd(&s_deg[pr.x - n0], 1);
        eid[pos] = pr.y;
    }
}

// ---------------------------------------------------------------------------
// K1: fused GEMM  [m, 0:384] = x[m,:] @ {fc_w0, fc_w1, skip_w}^T
//     jblk 0..3: writes bf16 f-tables + fused el/er attention dots
//     jblk 4..5: writes f32 hs (+skip_b)
// ---------------------------------------------------------------------------
__global__ __launch_bounds__(256) void k_gemm3(
    const float* __restrict__ x,
    const float* __restrict__ w0, const float* __restrict__ w1,
    const float* __restrict__ wsk, const float* __restrict__ skip_b,
    const float* __restrict__ al0, const float* __restrict__ ar0,
    const float* __restrict__ al1, const float* __restrict__ ar1,
    __hip_bfloat16* __restrict__ fb0, __hip_bfloat16* __restrict__ fb1,
    float* __restrict__ el0, float* __restrict__ er0,
    float* __restrict__ el1, float* __restrict__ er1,
    float* __restrict__ hs) {
    __shared__ float As[64][132];
    __shared__ float Bs[64][132];

    int tid = threadIdx.x;
    int m0 = blockIdx.y * 64;
    int jblk = blockIdx.x;                 // 0..5
    const float* W = (jblk < 2) ? w0 : (jblk < 4) ? w1 : wsk;
    int j0 = (jblk & 1) * 64;

    for (int i = 0; i < 8; i++) {
        int idx = tid * 8 + i;
        int row = idx >> 5;
        int c4 = idx & 31;
        float4 v = make_float4(0.f, 0.f, 0.f, 0.f);
        int gr = m0 + row;
        if (gr < N_NODES) v = *(const float4*)(x + (size_t)gr * HID + c4 * 4);
        *(float4*)(&As[row][c4 * 4]) = v;
        float4 wv = *(const float4*)(W + (size_t)(j0 + row) * HID + c4 * 4);
        *(float4*)(&Bs[row][c4 * 4]) = wv;
    }
    __syncthreads();

    int tx = tid & 15, ty = tid >> 4;
    float acc[4][4] = {};
    for (int k = 0; k < 128; k += 4) {
        float4 a[4], b[4];
#pragma unroll
        for (int i = 0; i < 4; i++) a[i] = *(const float4*)(&As[ty + 16 * i][k]);
#pragma unroll
        for (int j = 0; j < 4; j++) b[j] = *(const float4*)(&Bs[tx + 16 * j][k]);
#pragma unroll
        for (int i = 0; i < 4; i++)
#pragma unroll
            for (int j = 0; j < 4; j++)
                acc[i][j] += a[i].x * b[j].x + a[i].y * b[j].y +
                             a[i].z * b[j].z + a[i].w * b[j].w;
    }

    if (jblk < 4) {
        int rel = jblk >> 1;
        int h = jblk & 1;
        const float* al = rel ? al1 : al0;
        const float* ar = rel ? ar1 : ar0;
        float* elp = rel ? el1 : el0;
        float* erp = rel ? er1 : er0;
        __hip_bfloat16* fb = rel ? fb1 : fb0;

        float elv[4] = {0.f, 0.f, 0.f, 0.f};
        float erv[4] = {0.f, 0.f, 0.f, 0.f};
#pragma unroll
        for (int j = 0; j < 4; j++) {
            int col = j0 + tx + 16 * j;
            float av = al[col], rv = ar[col];
#pragma unroll
            for (int i = 0; i < 4; i++) {
                elv[i] += acc[i][j] * av;
                erv[i] += acc[i][j] * rv;
            }
        }
#pragma unroll
        for (int m = 1; m < 16; m <<= 1) {
#pragma unroll
            for (int i = 0; i < 4; i++) {
                elv[i] += __shfl_xor(elv[i], m);
                erv[i] += __shfl_xor(erv[i], m);
            }
        }
#pragma unroll
        for (int i = 0; i < 4; i++) {
            int gr = m0 + ty + 16 * i;
            if (gr >= N_NODES) continue;
#pragma unroll
            for (int j = 0; j < 4; j++) {
                int col = j0 + tx + 16 * j;
                fb[(size_t)gr * HID + col] = __float2bfloat16(acc[i][j]);
            }
            if (tx == 0) {
                elp[gr * 2 + h] = elv[i];
                erp[gr * 2 + h] = erv[i];
            }
        }
    } else {
#pragma unroll
        for (int i = 0; i < 4; i++) {
            int gr = m0 + ty + 16 * i;
            if (gr >= N_NODES) continue;
#pragma unroll
            for (int j = 0; j < 4; j++) {
                int col = j0 + tx + 16 * j;
                hs[(size_t)gr * HID + col] = acc[i][j] + skip_b[col];
            }
        }
    }
}

// ---------------------------------------------------------------------------
// K_aggregate: wave per dst node; lane-parallel softmax, readlane broadcast,
//              bf16 f gather. No atomics. offs has N+1 entries (sentinel).
// ---------------------------------------------------------------------------
__device__ __forceinline__ void agg_rel(const int* __restrict__ src,
                                        const float* __restrict__ ew,
                                        const int* __restrict__ offs,
                                        const int* __restrict__ eid,
                                        const float* __restrict__ el,
                                        const float* __restrict__ er,
                                        const __hip_bfloat16* __restrict__ fb,
                                        int n, int lane, int c,
                                        float& a0, float& a1, int h) {
    int b = offs[n];
    int e_end = offs[n + 1];
    int deg = e_end - b;
    if (deg <= 0) return;
    float ern0 = er[2 * n], ern1 = er[2 * n + 1];

    const int NC = 4;                       // cached chunks (256 edges)
    int cs[NC];
    float cw0[NC], cw1[NC];
    float d0 = 0.f, d1 = 0.f;
    int nchunk = (deg + 63) >> 6;
    for (int ch = 0; ch < nchunk; ch++) {
        int p = b + (ch << 6) + lane;
        int s = 0;
        float w0 = 0.f, w1 = 0.f;
        if (p < e_end) {
            int e = eid[p];
            s = src[e];
            float2 elv = *(const float2*)(el + 2 * s);
            float wgt = ew[e];
            float x0 = expf(leaky(elv.x + ern0));
            float x1 = expf(leaky(elv.y + ern1));
            d0 += x0;
            d1 += x1;
            w0 = x0 * wgt;
            w1 = x1 * wgt;
        }
        if (ch < NC) {
            cs[ch] = s;
            cw0[ch] = w0;
            cw1[ch] = w1;
        }
    }
#pragma unroll
    for (int m = 32; m; m >>= 1) {
        d0 += __shfl_xor(d0, m);
        d1 += __shfl_xor(d1, m);
    }
    float inv0 = 1.f / d0, inv1 = 1.f / d1;
    float invh = h ? inv1 : inv0;

    for (int ch = 0; ch < nchunk; ch++) {
        int cnt = deg - (ch << 6);
        if (cnt > 64) cnt = 64;
        int s;
        float w0, w1;
        if (ch < NC) {
            s = cs[ch];
            w0 = cw0[ch];
            w1 = cw1[ch];
        } else {                              // rare: recompute
            int p = b + (ch << 6) + lane;
            s = 0; w0 = 0.f; w1 = 0.f;
            if (p < e_end) {
                int e = eid[p];
                s = src[e];
                float2 elv = *(const float2*)(el + 2 * s);
                float wgt = ew[e];
                w0 = expf(leaky(elv.x + ern0)) * wgt;
                w1 = expf(leaky(elv.y + ern1)) * wgt;
            }
        }
        for (int j = 0; j < cnt; j++) {
            int sj = __shfl(s, j);
            float w0j = __shfl(w0, j);
            float w1j = __shfl(w1, j);
            float aj = (h ? w1j : w0j) * invh;
            __hip_bfloat162 fv =
                *(const __hip_bfloat162*)(fb + (size_t)sj * HID + c);
            a0 += aj * __bfloat162float(fv.x);
            a1 += aj * __bfloat162float(fv.y);
        }
    }
}

__global__ __launch_bounds__(256) void k_aggregate(
    const int* __restrict__ src0, const float* __restrict__ ew0,
    const int* __restrict__ offs0, const int* __restrict__ eid0,
    const float* __restrict__ el0, const float* __restrict__ er0,
    const __hip_bfloat16* __restrict__ fb0,
    const int* __restrict__ src1, const float* __restrict__ ew1,
    const int* __restrict__ offs1, const int* __restrict__ eid1,
    const float* __restrict__ el1, const float* __restrict__ er1,
    const __hip_bfloat16* __restrict__ fb1,
    const float* __restrict__ bias0, const float* __restrict__ bias1,
    float* __restrict__ acc) {
    int wave = threadIdx.x >> 6, lane = threadIdx.x & 63;
    int n = blockIdx.x * 4 + wave;
    if (n >= N_NODES) return;
    int h = lane >> 5;
    int c = lane * 2;
    float a0 = bias0[c] + bias1[c];
    float a1 = bias0[c + 1] + bias1[c + 1];
    agg_rel(src0, ew0, offs0, eid0, el0, er0, fb0, n, lane, c, a0, a1, h);
    agg_rel(src1, ew1, offs1, eid1, el1, er1, fb1, n, lane, c, a0, a1, h);
    float2 o = make_float2(fmaxf(a0, 0.f), fmaxf(a1, 0.f));   // relu folded
    *(float2*)(acc + (size_t)n * HID + c) = o;
}

// ---------------------------------------------------------------------------
// K4: h = hs + acc (acc already relu'd); per-column partial sums (double)
//     Launch with EXACTLY 512 blocks x 256 threads.
// ---------------------------------------------------------------------------
__global__ __launch_bounds__(256) void k_h_bn(float* __restrict__ h,
                                              const float* __restrict__ acc,
                                              double* __restrict__ psum,
                                              double* __restrict__ psumsq) {
    int tid = threadIdx.x;
    double s = 0.0, q = 0.0;
    const int total = N_NODES * HID;
    const int stride = 512 * 256;
    for (int idx = blockIdx.x * 256 + tid; idx < total; idx += stride) {
        float v = h[idx] + acc[idx];
        h[idx] = v;
        s += v;
        q += (double)v * v;
    }
    __shared__ double ls[256], lq[256];
    ls[tid] = s;
    lq[tid] = q;
    __syncthreads();
    if (tid < 128) {
        psum[blockIdx.x * 128 + tid] = ls[tid] + ls[tid + 128];
        psumsq[blockIdx.x * 128 + tid] = lq[tid] + lq[tid + 128];
    }
}

__global__ void k_bn_finalize(const double* __restrict__ psum,
                              const double* __restrict__ psumsq,
                              const float* __restrict__ gamma,
                              const float* __restrict__ beta,
                              float* __restrict__ ss) {
    int c = threadIdx.x;
    double s = 0.0, q = 0.0;
    for (int b = 0; b < 512; b++) {
        s += psum[b * 128 + c];
        q += psumsq[b * 128 + c];
    }
    double mu = s / N_NODES;
    double var = q / N_NODES - mu * mu;
    float sc = gamma[c] * (float)(1.0 / sqrt(var + (double)BN_EPS));
    ss[c] = sc;
    ss[128 + c] = beta[c] - (float)mu * sc;
}

__global__ __launch_bounds__(256) void k_classify(const float* __restrict__ h,
                                                  const float* __restrict__ ss,
                                                  const float* __restrict__ clf_w,
                                                  const float* __restrict__ clf_b,
                                                  float* __restrict__ out) {
    int wave = threadIdx.x >> 6, lane = threadIdx.x & 63;
    int n = blockIdx.x * 4 + wave;
    if (n >= N_NODES) return;
    float v0 = h[(size_t)n * HID + lane] * ss[lane] + ss[128 + lane];
    float v1 = h[(size_t)n * HID + 64 + lane] * ss[64 + lane] + ss[192 + lane];
    v0 = fmaxf(v0, 0.f);
    v1 = fmaxf(v1, 0.f);
#pragma unroll
    for (int k = 0; k < 16; k++) {
        float p = v0 * clf_w[k * 128 + lane] + v1 * clf_w[k * 128 + 64 + lane];
#pragma unroll
        for (int m = 32; m; m >>= 1) p += __shfl_xor(p, m);
        if (lane == 0) out[(size_t)n * 16 + k] = p + clf_b[k];
    }
}

// ---------------------------------------------------------------------------
extern "C" void kernel_launch(void* const* d_in, const int* in_sizes, int n_in,
                              void* d_out, int out_size, void* d_ws, size_t ws_size,
                              hipStream_t stream) {
    (void)in_sizes; (void)n_in; (void)out_size; (void)ws_size;
    const float* x      = (const float*)d_in[0];
    const int*   src0   = (const int*)d_in[1];
    const int*   dst0   = (const int*)d_in[2];
    const float* ew0    = (const float*)d_in[3];
    const int*   src1   = (const int*)d_in[4];
    const int*   dst1   = (const int*)d_in[5];
    const float* ew1    = (const float*)d_in[6];
    const float* fc_w0  = (const float*)d_in[7];
    const float* bias0  = (const float*)d_in[8];
    const float* al0    = (const float*)d_in[9];
    const float* ar0    = (const float*)d_in[10];
    const float* fc_w1  = (const float*)d_in[11];
    const float* bias1  = (const float*)d_in[12];
    const float* al1    = (const float*)d_in[13];
    const float* ar1    = (const float*)d_in[14];
    const float* skip_w = (const float*)d_in[15];
    const float* skip_b = (const float*)d_in[16];
    const float* gamma  = (const float*)d_in[17];
    const float* beta   = (const float*)d_in[18];
    const float* clf_w  = (const float*)d_in[19];
    const float* clf_b  = (const float*)d_in[20];
    float* out = (float*)d_out;

    char* wsp = (char*)d_ws;
    size_t off = 0;
    auto alloc = [&](size_t bytes) -> char* {
        char* p = wsp + off;
        off += (bytes + 255) & ~(size_t)255;
        return p;
    };
    __hip_bfloat16* fb0 = (__hip_bfloat16*)alloc((size_t)N_NODES * HID * 2);
    __hip_bfloat16* fb1 = (__hip_bfloat16*)alloc((size_t)N_NODES * HID * 2);
    float*  hs     = (float*)alloc((size_t)N_NODES * HID * 4);   // becomes h
    float*  acc    = (float*)alloc((size_t)N_NODES * HID * 4);
    float*  el0    = (float*)alloc((size_t)N_NODES * 2 * 4);
    float*  er0    = (float*)alloc((size_t)N_NODES * 2 * 4);
    float*  el1    = (float*)alloc((size_t)N_NODES * 2 * 4);
    float*  er1    = (float*)alloc((size_t)N_NODES * 2 * 4);
    int*    bincnt = (int*)alloc((size_t)2 * NBINS * NBLK * 4);
    int2*   pairs0 = (int2*)alloc((size_t)N_EDGES * 8);
    int2*   pairs1 = (int2*)alloc((size_t)N_EDGES * 8);
    int*    offs0  = (int*)alloc((size_t)(N_NODES + 1) * 4);
    int*    offs1  = (int*)alloc((size_t)(N_NODES + 1) * 4);
    int*    eid0   = (int*)alloc((size_t)N_EDGES * 4);
    int*    eid1   = (int*)alloc((size_t)N_EDGES * 4);
    double* psum   = (double*)alloc((size_t)512 * 128 * 8);
    double* psumsq = (double*)alloc((size_t)512 * 128 * 8);
    float*  ss     = (float*)alloc(256 * 4);

    // CSR build: binned counting sort, no global atomics, L2-local writes
    dim3 gbin(NBLK, 2);
    k_bincount<<<gbin, 256, 0, stream>>>(dst0, dst1, bincnt);
    k_binscan<<<2, 1024, 0, stream>>>(bincnt);
    k_binscatter<<<gbin, 256, 0, stream>>>(dst0, dst1, bincnt, pairs0, pairs1);
    dim3 gcsr(NBINS, 2);
    k_csr<<<gcsr, 256, 0, stream>>>(bincnt, pairs0, pairs1,
                                    offs0, offs1, eid0, eid1);

    // node features + fused attention dots + bf16 tables
    dim3 g1(6, (N_NODES + 63) / 64);
    k_gemm3<<<g1, 256, 0, stream>>>(x, fc_w0, fc_w1, skip_w, skip_b,
                                    al0, ar0, al1, ar1,
                                    fb0, fb1, el0, er0, el1, er1, hs);

    // gather-based aggregation (no atomics)
    k_aggregate<<<(N_NODES + 3) / 4, 256, 0, stream>>>(
        src0, ew0, offs0, eid0, el0, er0, fb0,
        src1, ew1, offs1, eid1, el1, er1, fb1,
        bias0, bias1, acc);

    k_h_bn<<<512, 256, 0, stream>>>(hs, acc, psum, psumsq);
    k_bn_finalize<<<1, 128, 0, stream>>>(psum, psumsq, gamma, beta, ss);
    k_classify<<<(N_NODES + 3) / 4, 256, 0, stream>>>(hs, ss, clf_w, clf_b, out);
}

// Round 5
// 306.193 us; speedup vs baseline: 3.3615x; 1.3358x over previous
//
#include <hip/hip_runtime.h>
#include <hip/hip_bf16.h>

// Problem constants (match reference)
#define N_NODES 50000
#define N_EDGES 800000
#define HID 128          // HEADS*HEAD_DIM
#define NEG_SLOPE 0.2f
#define BN_EPS 1e-5f

// CSR binning parameters
#define NBLK 256         // blocks over edges
#define BINSZ 512        // nodes per bin (power of 2)
#define BINSH 9
#define NBINS 98         // ceil(N_NODES / BINSZ)

typedef __bf16 v8bf __attribute__((ext_vector_type(8)));
typedef float v4f __attribute__((ext_vector_type(4)));

__device__ __forceinline__ float leaky(float v) {
    return (v > 0.f) ? v : v * NEG_SLOPE;
}
__device__ __forceinline__ unsigned short f2b(float f) {
    __hip_bfloat16 b = __float2bfloat16(f);
    return *reinterpret_cast<unsigned short*>(&b);
}

// ---------------------------------------------------------------------------
// K_prep: convert x and the 3 weight matrices to bf16 (vectorized)
// ---------------------------------------------------------------------------
__global__ __launch_bounds__(256) void k_prep(const float* __restrict__ x,
                                              const float* __restrict__ w0,
                                              const float* __restrict__ w1,
                                              const float* __restrict__ wsk,
                                              unsigned short* __restrict__ xb,
                                              unsigned short* __restrict__ wb) {
    const int XQ = N_NODES * HID / 4;     // 1,600,000 quads
    const int WQ = 128 * 128 / 4;         // 4096 quads per matrix
    int q = blockIdx.x * 256 + threadIdx.x;
    if (q < XQ) {
        float4 v = ((const float4*)x)[q];
        ushort4 o;
        o.x = f2b(v.x); o.y = f2b(v.y); o.z = f2b(v.z); o.w = f2b(v.w);
        *(ushort4*)(xb + (size_t)q * 4) = o;
    } else {
        int qw = q - XQ;
        if (qw < 3 * WQ) {
            int mat = qw >> 12;
            int rem = qw & 4095;
            const float* W = (mat == 0) ? w0 : (mat == 1) ? w1 : wsk;
            float4 v = ((const float4*)W)[rem];
            ushort4 o;
            o.x = f2b(v.x); o.y = f2b(v.y); o.z = f2b(v.z); o.w = f2b(v.w);
            *(ushort4*)(wb + (size_t)mat * 16384 + rem * 4) = o;
        }
    }
}

// ---------------------------------------------------------------------------
// CSR pass A: per-block LDS histogram of dst bins. grid: (NBLK, 2)
// ---------------------------------------------------------------------------
__global__ __launch_bounds__(256) void k_bincount(const int* __restrict__ dst0,
                                                  const int* __restrict__ dst1,
                                                  int* __restrict__ bincnt) {
    int rel = blockIdx.y;
    const int* dst = rel ? dst1 : dst0;
    __shared__ int cnt[NBINS];
    for (int i = threadIdx.x; i < NBINS; i += 256) cnt[i] = 0;
    __syncthreads();
    const int CH = (N_EDGES + NBLK - 1) / NBLK;   // 3125
    int b0 = blockIdx.x * CH;
    int b1 = min(N_EDGES, b0 + CH);
    for (int e = b0 + threadIdx.x; e < b1; e += 256)
        atomicAdd(&cnt[dst[e] >> BINSH], 1);
    __syncthreads();
    for (int i = threadIdx.x; i < NBINS; i += 256)
        bincnt[rel * NBINS * NBLK + i * NBLK + blockIdx.x] = cnt[i];
}

// ---------------------------------------------------------------------------
// CSR pass B: in-place exclusive scan of bincnt per relation. grid: (2)
// ---------------------------------------------------------------------------
__global__ __launch_bounds__(1024) void k_binscan(int* __restrict__ bincnt) {
    int* a = bincnt + blockIdx.x * NBINS * NBLK;
    const int TOT = NBINS * NBLK;                 // 25088
    const int CH = (TOT + 1023) / 1024;           // 25
    int tid = threadIdx.x;
    int base = tid * CH;
    int lv[CH];
    int sum = 0;
    for (int i = 0; i < CH; i++) {
        int idx = base + i;
        int v = (idx < TOT) ? a[idx] : 0;
        lv[i] = sum;
        sum += v;
    }
    __shared__ int ls[1024];
    ls[tid] = sum;
    __syncthreads();
    for (int ofs = 1; ofs < 1024; ofs <<= 1) {
        int v = (tid >= ofs) ? ls[tid - ofs] : 0;
        __syncthreads();
        ls[tid] += v;
        __syncthreads();
    }
    int pre = tid ? ls[tid - 1] : 0;
    for (int i = 0; i < CH; i++) {
        int idx = base + i;
        if (idx < TOT) a[idx] = pre + lv[i];
    }
}

// ---------------------------------------------------------------------------
// CSR pass C: scatter (dst,eid) into per-(bin,block) contiguous runs.
// grid: (NBLK, 2)
// ---------------------------------------------------------------------------
__global__ __launch_bounds__(256) void k_binscatter(const int* __restrict__ dst0,
                                                    const int* __restrict__ dst1,
                                                    const int* __restrict__ bincnt,
                                                    int2* __restrict__ pairs0,
                                                    int2* __restrict__ pairs1) {
    int rel = blockIdx.y;
    const int* dst = rel ? dst1 : dst0;
    int2* pairs = rel ? pairs1 : pairs0;
    __shared__ int cur[NBINS];
    for (int i = threadIdx.x; i < NBINS; i += 256)
        cur[i] = bincnt[rel * NBINS * NBLK + i * NBLK + blockIdx.x];
    __syncthreads();
    const int CH = (N_EDGES + NBLK - 1) / NBLK;
    int b0 = blockIdx.x * CH;
    int b1 = min(N_EDGES, b0 + CH);
    for (int e = b0 + threadIdx.x; e < b1; e += 256) {
        int d = dst[e];
        int pos = atomicAdd(&cur[d >> BINSH], 1);
        pairs[pos] = make_int2(d, e);
    }
}

// ---------------------------------------------------------------------------
// CSR pass D: per (rel,bin): LDS histogram -> scan -> offs (+sentinel) ->
// place 16B edge records (src, ew, el0, el1) sorted by dst. grid: (NBINS, 2)
// Runs AFTER the GEMM (needs el).
// ---------------------------------------------------------------------------
__global__ __launch_bounds__(256) void k_csr(const int* __restrict__ bincnt,
                                             const int2* __restrict__ pairs0,
                                             const int2* __restrict__ pairs1,
                                             const int* __restrict__ src0,
                                             const float* __restrict__ ew0,
                                             const float* __restrict__ el0,
                                             const int* __restrict__ src1,
                                             const float* __restrict__ ew1,
                                             const float* __restrict__ el1,
                                             int* __restrict__ offs0,
                                             int* __restrict__ offs1,
                                             int4* __restrict__ rec0,
                                             int4* __restrict__ rec1) {
    int rel = blockIdx.y;
    const int2* pairs = rel ? pairs1 : pairs0;
    const int* src = rel ? src1 : src0;
    const float* ew = rel ? ew1 : ew0;
    const float* el = rel ? el1 : el0;
    int* offs = rel ? offs1 : offs0;
    int4* rec = rel ? rec1 : rec0;
    int bin = blockIdx.x;
    int tid = threadIdx.x;
    const int* bc = bincnt + rel * NBINS * NBLK;
    int pbase = bc[bin * NBLK];
    int pend = (bin < NBINS - 1) ? bc[(bin + 1) * NBLK] : N_EDGES;
    int n0 = bin << BINSH;
    int nn = min(N_NODES - n0, BINSZ);

    __shared__ int s_deg[BINSZ];
    __shared__ int s_ts[256];
    for (int i = tid; i < BINSZ; i += 256) s_deg[i] = 0;
    __syncthreads();
    for (int p = pbase + tid; p < pend; p += 256)
        atomicAdd(&s_deg[pairs[p].x - n0], 1);
    __syncthreads();

    // 256-thread exclusive scan over 512 (2 per thread)
    int d0 = s_deg[tid * 2], d1 = s_deg[tid * 2 + 1];
    s_ts[tid] = d0 + d1;
    __syncthreads();
    for (int ofs = 1; ofs < 256; ofs <<= 1) {
        int v = (tid >= ofs) ? s_ts[tid - ofs] : 0;
        __syncthreads();
        s_ts[tid] += v;
        __syncthreads();
    }
    int pre = tid ? s_ts[tid - 1] : 0;
    s_deg[tid * 2] = pbase + pre;
    s_deg[tid * 2 + 1] = pbase + pre + d0;
    __syncthreads();

    for (int l = tid; l < nn; l += 256) offs[n0 + l] = s_deg[l];
    if (bin == NBINS - 1 && tid == 0) offs[N_NODES] = N_EDGES;
    __syncthreads();

    for (int p = pbase + tid; p < pend; p += 256) {
        int2 pr = pairs[p];
        int pos = atomicAdd(&s_deg[pr.x - n0], 1);
        int e = pr.y;
        int s = src[e];
        float2 ev = *(const float2*)(el + 2 * s);
        int4 r;
        r.x = s;
        r.y = __float_as_int(ew[e]);
        r.z = __float_as_int(ev.x);
        r.w = __float_as_int(ev.y);
        rec[pos] = r;
    }
}

// ---------------------------------------------------------------------------
// K1: MFMA GEMM  [m, 0:384] = x @ {fc_w0, fc_w1, skip_w}^T  (bf16 in, f32 acc)
// grid (6, 782). Block = 4 waves; wave = 16 rows x 64 cols.
// jblk 0..3: bf16 f-tables + fused el/er; jblk 4..5: f32 hs (+skip_b)
// ---------------------------------------------------------------------------
__global__ __launch_bounds__(256) void k_gemm_mfma(
    const unsigned short* __restrict__ xb, const unsigned short* __restrict__ wb,
    const float* __restrict__ skip_b,
    const float* __restrict__ al0, const float* __restrict__ ar0,
    const float* __restrict__ al1, const float* __restrict__ ar1,
    unsigned short* __restrict__ fb0, unsigned short* __restrict__ fb1,
    float* __restrict__ el0, float* __restrict__ er0,
    float* __restrict__ el1, float* __restrict__ er1,
    float* __restrict__ hs) {
    __shared__ unsigned short As[64][128];
    __shared__ unsigned short Bs[64][128];
    int tid = threadIdx.x;
    int jblk = blockIdx.x;                // 0..5
    int mat = jblk >> 1;                  // 0=fc_w0, 1=fc_w1, 2=skip_w
    int j0 = (jblk & 1) * 64;
    int m0 = blockIdx.y * 64;

    // stage A (x rows) and B (weight rows) tiles, 16B per thread-iter
#pragma unroll
    for (int i = 0; i < 4; i++) {
        int idx = tid * 4 + i;            // 0..1023
        int row = idx >> 4, seg = idx & 15;
        uint4 v = make_uint4(0, 0, 0, 0);
        int gr = m0 + row;
        if (gr < N_NODES) v = *(const uint4*)(xb + (size_t)gr * HID + seg * 8);
        *(uint4*)(&As[row][seg * 8]) = v;
        uint4 wv = *(const uint4*)(wb + (size_t)mat * 16384 +
                                   (size_t)(j0 + row) * HID + seg * 8);
        *(uint4*)(&Bs[row][seg * 8]) = wv;
    }
    __syncthreads();

    int w = tid >> 6, l = tid & 63;
    int lr = l & 15, lg = l >> 4;
    v8bf afrag[4];
#pragma unroll
    for (int kb = 0; kb < 4; kb++)
        afrag[kb] = *(v8bf*)(&As[w * 16 + lr][kb * 32 + lg * 8]);
    v4f acc[4] = {};
#pragma unroll
    for (int nt = 0; nt < 4; nt++)
#pragma unroll
        for (int kb = 0; kb < 4; kb++) {
            v8bf bfrag = *(v8bf*)(&Bs[nt * 16 + lr][kb * 32 + lg * 8]);
            acc[nt] = __builtin_amdgcn_mfma_f32_16x16x32_bf16(afrag[kb], bfrag,
                                                              acc[nt], 0, 0, 0);
        }

    // C/D layout: col = lane&15, row = (lane>>4)*4 + r   [m89-verified]
    if (mat < 2) {
        int h = jblk & 1;
        const float* al = mat ? al1 : al0;
        const float* ar = mat ? ar1 : ar0;
        float* elp = mat ? el1 : el0;
        float* erp = mat ? er1 : er0;
        unsigned short* fbp = mat ? fb1 : fb0;
        float elv[4] = {0.f, 0.f, 0.f, 0.f};
        float erv[4] = {0.f, 0.f, 0.f, 0.f};
#pragma unroll
        for (int nt = 0; nt < 4; nt++) {
            int colg = j0 + nt * 16 + lr;
            float av = al[colg], rv = ar[colg];
#pragma unroll
            for (int r = 0; r < 4; r++) {
                elv[r] += acc[nt][r] * av;
                erv[r] += acc[nt][r] * rv;
            }
        }
#pragma unroll
        for (int m = 1; m < 16; m <<= 1)
#pragma unroll
            for (int r = 0; r < 4; r++) {
                elv[r] += __shfl_xor(elv[r], m);
                erv[r] += __shfl_xor(erv[r], m);
            }
#pragma unroll
        for (int r = 0; r < 4; r++) {
            int grow = m0 + w * 16 + lg * 4 + r;
            if (grow >= N_NODES) continue;
#pragma unroll
            for (int nt = 0; nt < 4; nt++) {
                int colg = j0 + nt * 16 + lr;
                fbp[(size_t)grow * HID + colg] = f2b(acc[nt][r]);
            }
            if (lr == 0) {
                elp[grow * 2 + h] = elv[r];
                erp[grow * 2 + h] = erv[r];
            }
        }
    } else {
#pragma unroll
        for (int r = 0; r < 4; r++) {
            int grow = m0 + w * 16 + lg * 4 + r;
            if (grow >= N_NODES) continue;
#pragma unroll
            for (int nt = 0; nt < 4; nt++) {
                int colg = j0 + nt * 16 + lr;
                hs[(size_t)grow * HID + colg] = acc[nt][r] + skip_b[colg];
            }
        }
    }
}

// ---------------------------------------------------------------------------
// K_aggregate: wave per dst node. Sequential 16B edge records; gather loop
// processes 4 edges/iter (16 lanes x 16B per edge). Writes h in place.
// ---------------------------------------------------------------------------
__device__ __forceinline__ void agg_rel2(const int* __restrict__ offs,
                                         const int4* __restrict__ rec,
                                         const float* __restrict__ er,
                                         const unsigned short* __restrict__ fb,
                                         int n, int lane, int cb, int sub,
                                         int hh, float* a) {
    int b = offs[n];
    int e_end = offs[n + 1];
    int deg = e_end - b;
    if (deg <= 0) return;
    float ern0 = er[2 * n], ern1 = er[2 * n + 1];

    const int NC = 4;
    int cs[NC];
    float cw0[NC], cw1[NC];
    float d0 = 0.f, d1 = 0.f;
    int nchunk = (deg + 63) >> 6;
    for (int ch = 0; ch < nchunk; ch++) {
        int p = b + (ch << 6) + lane;
        int s = 0;
        float w0 = 0.f, w1 = 0.f;
        if (p < e_end) {
            int4 r = rec[p];
            s = r.x;
            float wgt = __int_as_float(r.y);
            float x0 = expf(leaky(__int_as_float(r.z) + ern0));
            float x1 = expf(leaky(__int_as_float(r.w) + ern1));
            d0 += x0;
            d1 += x1;
            w0 = x0 * wgt;
            w1 = x1 * wgt;
        }
        if (ch < NC) {
            cs[ch] = s;
            cw0[ch] = w0;
            cw1[ch] = w1;
        }
    }
#pragma unroll
    for (int m = 32; m; m >>= 1) {
        d0 += __shfl_xor(d0, m);
        d1 += __shfl_xor(d1, m);
    }
    float invh = 1.f / (hh ? d1 : d0);

    for (int ch = 0; ch < nchunk; ch++) {
        int s;
        float w0, w1;
        if (ch < NC) {
            s = cs[ch];
            w0 = cw0[ch];
            w1 = cw1[ch];
        } else {
            int p = b + (ch << 6) + lane;
            s = 0;
            w0 = 0.f;
            w1 = 0.f;
            if (p < e_end) {
                int4 r = rec[p];
                s = r.x;
                float wgt = __int_as_float(r.y);
                w0 = expf(leaky(__int_as_float(r.z) + ern0)) * wgt;
                w1 = expf(leaky(__int_as_float(r.w) + ern1)) * wgt;
            }
        }
        int cnt = deg - (ch << 6);
        if (cnt > 64) cnt = 64;
        int ng = (cnt + 3) >> 2;
        for (int g = 0; g < ng; g++) {
            int sl = (g << 2) + sub;
            int sj = __shfl(s, sl);
            float w0j = __shfl(w0, sl);
            float w1j = __shfl(w1, sl);
            float aj = (hh ? w1j : w0j) * invh;
            uint4 fv = *(const uint4*)(fb + (size_t)sj * HID + cb * 8);
            a[0] += aj * __uint_as_float(fv.x << 16);
            a[1] += aj * __uint_as_float(fv.x & 0xffff0000u);
            a[2] += aj * __uint_as_float(fv.y << 16);
            a[3] += aj * __uint_as_float(fv.y & 0xffff0000u);
            a[4] += aj * __uint_as_float(fv.z << 16);
            a[5] += aj * __uint_as_float(fv.z & 0xffff0000u);
            a[6] += aj * __uint_as_float(fv.w << 16);
            a[7] += aj * __uint_as_float(fv.w & 0xffff0000u);
        }
    }
}

__global__ __launch_bounds__(256) void k_aggregate(
    const int* __restrict__ offs0, const int4* __restrict__ rec0,
    const float* __restrict__ er0, const unsigned short* __restrict__ fb0,
    const int* __restrict__ offs1, const int4* __restrict__ rec1,
    const float* __restrict__ er1, const unsigned short* __restrict__ fb1,
    const float* __restrict__ bias0, const float* __restrict__ bias1,
    float* __restrict__ h) {
    int wave = threadIdx.x >> 6, lane = threadIdx.x & 63;
    int n = blockIdx.x * 4 + wave;
    if (n >= N_NODES) return;
    int cb = lane & 15;        // col block: cols cb*8 .. cb*8+7
    int sub = lane >> 4;       // sub-edge slot
    int hh = cb >> 3;          // head of these cols
    float a[8] = {0.f, 0.f, 0.f, 0.f, 0.f, 0.f, 0.f, 0.f};
    agg_rel2(offs0, rec0, er0, fb0, n, lane, cb, sub, hh, a);
    agg_rel2(offs1, rec1, er1, fb1, n, lane, cb, sub, hh, a);
#pragma unroll
    for (int j = 0; j < 8; j++) {
        a[j] += __shfl_xor(a[j], 16);
        a[j] += __shfl_xor(a[j], 32);
    }
    if (sub == 0) {
        size_t base = (size_t)n * HID + cb * 8;
        float4 v0 = *(const float4*)(h + base);
        float4 v1 = *(const float4*)(h + base + 4);
        int c0 = cb * 8;
        float4 o0, o1;
        o0.x = v0.x + fmaxf(a[0] + bias0[c0 + 0] + bias1[c0 + 0], 0.f);
        o0.y = v0.y + fmaxf(a[1] + bias0[c0 + 1] + bias1[c0 + 1], 0.f);
        o0.z = v0.z + fmaxf(a[2] + bias0[c0 + 2] + bias1[c0 + 2], 0.f);
        o0.w = v0.w + fmaxf(a[3] + bias0[c0 + 3] + bias1[c0 + 3], 0.f);
        o1.x = v1.x + fmaxf(a[4] + bias0[c0 + 4] + bias1[c0 + 4], 0.f);
        o1.y = v1.y + fmaxf(a[5] + bias0[c0 + 5] + bias1[c0 + 5], 0.f);
        o1.z = v1.z + fmaxf(a[6] + bias0[c0 + 6] + bias1[c0 + 6], 0.f);
        o1.w = v1.w + fmaxf(a[7] + bias0[c0 + 7] + bias1[c0 + 7], 0.f);
        *(float4*)(h + base) = o0;
        *(float4*)(h + base + 4) = o1;
    }
}

// ---------------------------------------------------------------------------
// K_bnstats: per-column partial sums over h. EXACTLY 512 blocks x 256 threads.
// ---------------------------------------------------------------------------
__global__ __launch_bounds__(256) void k_bnstats(const float* __restrict__ h,
                                                 double* __restrict__ psum,
                                                 double* __restrict__ psumsq) {
    int tid = threadIdx.x;
    double s = 0.0, q = 0.0;
    const int total = N_NODES * HID;
    const int stride = 512 * 256;
    for (int idx = blockIdx.x * 256 + tid; idx < total; idx += stride) {
        float v = h[idx];
        s += v;
        q += (double)v * v;
    }
    __shared__ double ls[256], lq[256];
    ls[tid] = s;
    lq[tid] = q;
    __syncthreads();
    if (tid < 128) {
        psum[blockIdx.x * 128 + tid] = ls[tid] + ls[tid + 128];
        psumsq[blockIdx.x * 128 + tid] = lq[tid] + lq[tid + 128];
    }
}

__global__ void k_bn_finalize(const double* __restrict__ psum,
                              const double* __restrict__ psumsq,
                              const float* __restrict__ gamma,
                              const float* __restrict__ beta,
                              float* __restrict__ ss) {
    int c = threadIdx.x;
    double s = 0.0, q = 0.0;
    for (int b = 0; b < 512; b++) {
        s += psum[b * 128 + c];
        q += psumsq[b * 128 + c];
    }
    double mu = s / N_NODES;
    double var = q / N_NODES - mu * mu;
    float sc = gamma[c] * (float)(1.0 / sqrt(var + (double)BN_EPS));
    ss[c] = sc;
    ss[128 + c] = beta[c] - (float)mu * sc;
}

__global__ __launch_bounds__(256) void k_classify(const float* __restrict__ h,
                                                  const float* __restrict__ ss,
                                                  const float* __restrict__ clf_w,
                                                  const float* __restrict__ clf_b,
                                                  float* __restrict__ out) {
    int wave = threadIdx.x >> 6, lane = threadIdx.x & 63;
    int n = blockIdx.x * 4 + wave;
    if (n >= N_NODES) return;
    float v0 = h[(size_t)n * HID + lane] * ss[lane] + ss[128 + lane];
    float v1 = h[(size_t)n * HID + 64 + lane] * ss[64 + lane] + ss[192 + lane];
    v0 = fmaxf(v0, 0.f);
    v1 = fmaxf(v1, 0.f);
#pragma unroll
    for (int k = 0; k < 16; k++) {
        float p = v0 * clf_w[k * 128 + lane] + v1 * clf_w[k * 128 + 64 + lane];
#pragma unroll
        for (int m = 32; m; m >>= 1) p += __shfl_xor(p, m);
        if (lane == 0) out[(size_t)n * 16 + k] = p + clf_b[k];
    }
}

// ---------------------------------------------------------------------------
extern "C" void kernel_launch(void* const* d_in, const int* in_sizes, int n_in,
                              void* d_out, int out_size, void* d_ws, size_t ws_size,
                              hipStream_t stream) {
    (void)in_sizes; (void)n_in; (void)out_size; (void)ws_size;
    const float* x      = (const float*)d_in[0];
    const int*   src0   = (const int*)d_in[1];
    const int*   dst0   = (const int*)d_in[2];
    const float* ew0    = (const float*)d_in[3];
    const int*   src1   = (const int*)d_in[4];
    const int*   dst1   = (const int*)d_in[5];
    const float* ew1    = (const float*)d_in[6];
    const float* fc_w0  = (const float*)d_in[7];
    const float* bias0  = (const float*)d_in[8];
    const float* al0    = (const float*)d_in[9];
    const float* ar0    = (const float*)d_in[10];
    const float* fc_w1  = (const float*)d_in[11];
    const float* bias1  = (const float*)d_in[12];
    const float* al1    = (const float*)d_in[13];
    const float* ar1    = (const float*)d_in[14];
    const float* skip_w = (const float*)d_in[15];
    const float* skip_b = (const float*)d_in[16];
    const float* gamma  = (const float*)d_in[17];
    const float* beta   = (const float*)d_in[18];
    const float* clf_w  = (const float*)d_in[19];
    const float* clf_b  = (const float*)d_in[20];
    float* out = (float*)d_out;

    char* wsp = (char*)d_ws;
    size_t off = 0;
    auto alloc = [&](size_t bytes) -> char* {
        char* p = wsp + off;
        off += (bytes + 255) & ~(size_t)255;
        return p;
    };
    unsigned short* xb  = (unsigned short*)alloc((size_t)N_NODES * HID * 2);
    unsigned short* wb  = (unsigned short*)alloc((size_t)3 * 16384 * 2);
    unsigned short* fb0 = (unsigned short*)alloc((size_t)N_NODES * HID * 2);
    unsigned short* fb1 = (unsigned short*)alloc((size_t)N_NODES * HID * 2);
    float*  hs     = (float*)alloc((size_t)N_NODES * HID * 4);   // becomes h
    float*  el0    = (float*)alloc((size_t)N_NODES * 2 * 4);
    float*  er0    = (float*)alloc((size_t)N_NODES * 2 * 4);
    float*  el1    = (float*)alloc((size_t)N_NODES * 2 * 4);
    float*  er1    = (float*)alloc((size_t)N_NODES * 2 * 4);
    int*    bincnt = (int*)alloc((size_t)2 * NBINS * NBLK * 4);
    int2*   pairs0 = (int2*)alloc((size_t)N_EDGES * 8);
    int2*   pairs1 = (int2*)alloc((size_t)N_EDGES * 8);
    int*    offs0  = (int*)alloc((size_t)(N_NODES + 1) * 4);
    int*    offs1  = (int*)alloc((size_t)(N_NODES + 1) * 4);
    int4*   rec0   = (int4*)alloc((size_t)N_EDGES * 16);
    int4*   rec1   = (int4*)alloc((size_t)N_EDGES * 16);
    double* psum   = (double*)alloc((size_t)512 * 128 * 8);
    double* psumsq = (double*)alloc((size_t)512 * 128 * 8);
    float*  ss     = (float*)alloc(256 * 4);

    // bf16 conversion of x and weights
    k_prep<<<6299, 256, 0, stream>>>(x, fc_w0, fc_w1, skip_w, xb, wb);

    // CSR binning (independent of GEMM)
    dim3 gbin(NBLK, 2);
    k_bincount<<<gbin, 256, 0, stream>>>(dst0, dst1, bincnt);
    k_binscan<<<2, 1024, 0, stream>>>(bincnt);
    k_binscatter<<<gbin, 256, 0, stream>>>(dst0, dst1, bincnt, pairs0, pairs1);

    // MFMA GEMM + fused attention dots + bf16 tables + hs
    dim3 g1(6, (N_NODES + 63) / 64);
    k_gemm_mfma<<<g1, 256, 0, stream>>>(xb, wb, skip_b, al0, ar0, al1, ar1,
                                        fb0, fb1, el0, er0, el1, er1, hs);

    // CSR finalize: sorted 16B edge records (needs el)
    dim3 gcsr(NBINS, 2);
    k_csr<<<gcsr, 256, 0, stream>>>(bincnt, pairs0, pairs1,
                                    src0, ew0, el0, src1, ew1, el1,
                                    offs0, offs1, rec0, rec1);

    // gather aggregation, h = hs + relu(bias + msgs) in place
    k_aggregate<<<(N_NODES + 3) / 4, 256, 0, stream>>>(
        offs0, rec0, er0, fb0, offs1, rec1, er1, fb1, bias0, bias1, hs);

    k_bnstats<<<512, 256, 0, stream>>>(hs, psum, psumsq);
    k_bn_finalize<<<1, 128, 0, stream>>>(psum, psumsq, gamma, beta, ss);
    k_classify<<<(N_NODES + 3) / 4, 256, 0, stream>>>(hs, ss, clf_w, clf_b, out);
}

// Round 6
// 278.897 us; speedup vs baseline: 3.6905x; 1.0979x over previous
//
#include <hip/hip_runtime.h>
#include <hip/hip_bf16.h>

// Problem constants (match reference)
#define N_NODES 50000
#define N_EDGES 800000
#define HID 128          // HEADS*HEAD_DIM
#define NEG_SLOPE 0.2f
#define BN_EPS 1e-5f

// CSR binning parameters
#define NBLK 256         // blocks over edges
#define BINSZ 512        // nodes per bin (power of 2)
#define BINSH 9
#define NBINS 98         // ceil(N_NODES / BINSZ)

typedef __bf16 v8bf __attribute__((ext_vector_type(8)));
typedef float v4f __attribute__((ext_vector_type(4)));

__device__ __forceinline__ float leaky(float v) {
    return (v > 0.f) ? v : v * NEG_SLOPE;
}
__device__ __forceinline__ unsigned short f2b(float f) {
    __hip_bfloat16 b = __float2bfloat16(f);
    return *reinterpret_cast<unsigned short*>(&b);
}

// ---------------------------------------------------------------------------
// K_prep: convert x and the 3 weight matrices to bf16 (vectorized)
// ---------------------------------------------------------------------------
__global__ __launch_bounds__(256) void k_prep(const float* __restrict__ x,
                                              const float* __restrict__ w0,
                                              const float* __restrict__ w1,
                                              const float* __restrict__ wsk,
                                              unsigned short* __restrict__ xb,
                                              unsigned short* __restrict__ wb) {
    const int XQ = N_NODES * HID / 4;     // 1,600,000 quads
    const int WQ = 128 * 128 / 4;         // 4096 quads per matrix
    int q = blockIdx.x * 256 + threadIdx.x;
    if (q < XQ) {
        float4 v = ((const float4*)x)[q];
        ushort4 o;
        o.x = f2b(v.x); o.y = f2b(v.y); o.z = f2b(v.z); o.w = f2b(v.w);
        *(ushort4*)(xb + (size_t)q * 4) = o;
    } else {
        int qw = q - XQ;
        if (qw < 3 * WQ) {
            int mat = qw >> 12;
            int rem = qw & 4095;
            const float* W = (mat == 0) ? w0 : (mat == 1) ? w1 : wsk;
            float4 v = ((const float4*)W)[rem];
            ushort4 o;
            o.x = f2b(v.x); o.y = f2b(v.y); o.z = f2b(v.z); o.w = f2b(v.w);
            *(ushort4*)(wb + (size_t)mat * 16384 + rem * 4) = o;
        }
    }
}

// ---------------------------------------------------------------------------
// CSR pass A: per-block LDS histogram of dst bins. grid: (NBLK, 2)
// ---------------------------------------------------------------------------
__global__ __launch_bounds__(256) void k_bincount(const int* __restrict__ dst0,
                                                  const int* __restrict__ dst1,
                                                  int* __restrict__ bincnt) {
    int rel = blockIdx.y;
    const int* dst = rel ? dst1 : dst0;
    __shared__ int cnt[NBINS];
    for (int i = threadIdx.x; i < NBINS; i += 256) cnt[i] = 0;
    __syncthreads();
    const int CH = (N_EDGES + NBLK - 1) / NBLK;   // 3125
    int b0 = blockIdx.x * CH;
    int b1 = min(N_EDGES, b0 + CH);
    for (int e = b0 + threadIdx.x; e < b1; e += 256)
        atomicAdd(&cnt[dst[e] >> BINSH], 1);
    __syncthreads();
    for (int i = threadIdx.x; i < NBINS; i += 256)
        bincnt[rel * NBINS * NBLK + i * NBLK + blockIdx.x] = cnt[i];
}

// ---------------------------------------------------------------------------
// CSR pass B: in-place exclusive scan of bincnt per relation. grid: (2)
// ---------------------------------------------------------------------------
__global__ __launch_bounds__(1024) void k_binscan(int* __restrict__ bincnt) {
    int* a = bincnt + blockIdx.x * NBINS * NBLK;
    const int TOT = NBINS * NBLK;                 // 25088
    const int CH = (TOT + 1023) / 1024;           // 25
    int tid = threadIdx.x;
    int base = tid * CH;
    int lv[CH];
    int sum = 0;
    for (int i = 0; i < CH; i++) {
        int idx = base + i;
        int v = (idx < TOT) ? a[idx] : 0;
        lv[i] = sum;
        sum += v;
    }
    __shared__ int ls[1024];
    ls[tid] = sum;
    __syncthreads();
    for (int ofs = 1; ofs < 1024; ofs <<= 1) {
        int v = (tid >= ofs) ? ls[tid - ofs] : 0;
        __syncthreads();
        ls[tid] += v;
        __syncthreads();
    }
    int pre = tid ? ls[tid - 1] : 0;
    for (int i = 0; i < CH; i++) {
        int idx = base + i;
        if (idx < TOT) a[idx] = pre + lv[i];
    }
}

// ---------------------------------------------------------------------------
// CSR pass C: scatter (dst,src,ew) into per-(bin,block) contiguous runs.
// src/ew read coalesced here (e-sequential) so k_csr needn't gather them.
// grid: (NBLK, 2)
// ---------------------------------------------------------------------------
__global__ __launch_bounds__(256) void k_binscatter(const int* __restrict__ dst0,
                                                    const int* __restrict__ dst1,
                                                    const int* __restrict__ src0,
                                                    const int* __restrict__ src1,
                                                    const float* __restrict__ ew0,
                                                    const float* __restrict__ ew1,
                                                    const int* __restrict__ bincnt,
                                                    int4* __restrict__ pairs0,
                                                    int4* __restrict__ pairs1) {
    int rel = blockIdx.y;
    const int* dst = rel ? dst1 : dst0;
    const int* src = rel ? src1 : src0;
    const float* ew = rel ? ew1 : ew0;
    int4* pairs = rel ? pairs1 : pairs0;
    __shared__ int cur[NBINS];
    for (int i = threadIdx.x; i < NBINS; i += 256)
        cur[i] = bincnt[rel * NBINS * NBLK + i * NBLK + blockIdx.x];
    __syncthreads();
    const int CH = (N_EDGES + NBLK - 1) / NBLK;
    int b0 = blockIdx.x * CH;
    int b1 = min(N_EDGES, b0 + CH);
    for (int e = b0 + threadIdx.x; e < b1; e += 256) {
        int d = dst[e];
        int pos = atomicAdd(&cur[d >> BINSH], 1);
        pairs[pos] = make_int4(d, src[e], __float_as_int(ew[e]), 0);
    }
}

// ---------------------------------------------------------------------------
// CSR pass D: per (rel,bin): LDS histogram -> scan -> offs (+sentinel) ->
// place 16B edge records (src, ew, el0, el1) sorted by dst. grid: (NBINS, 2)
// Runs AFTER the GEMM (needs el). Only el is a random gather (8B/edge).
// ---------------------------------------------------------------------------
__global__ __launch_bounds__(256) void k_csr(const int* __restrict__ bincnt,
                                             const int4* __restrict__ pairs0,
                                             const int4* __restrict__ pairs1,
                                             const float* __restrict__ el0,
                                             const float* __restrict__ el1,
                                             int* __restrict__ offs0,
                                             int* __restrict__ offs1,
                                             int4* __restrict__ rec0,
                                             int4* __restrict__ rec1) {
    int rel = blockIdx.y;
    const int4* pairs = rel ? pairs1 : pairs0;
    const float* el = rel ? el1 : el0;
    int* offs = rel ? offs1 : offs0;
    int4* rec = rel ? rec1 : rec0;
    int bin = blockIdx.x;
    int tid = threadIdx.x;
    const int* bc = bincnt + rel * NBINS * NBLK;
    int pbase = bc[bin * NBLK];
    int pend = (bin < NBINS - 1) ? bc[(bin + 1) * NBLK] : N_EDGES;
    int n0 = bin << BINSH;
    int nn = min(N_NODES - n0, BINSZ);

    __shared__ int s_deg[BINSZ];
    __shared__ int s_ts[256];
    for (int i = tid; i < BINSZ; i += 256) s_deg[i] = 0;
    __syncthreads();
    for (int p = pbase + tid; p < pend; p += 256)
        atomicAdd(&s_deg[pairs[p].x - n0], 1);
    __syncthreads();

    int d0 = s_deg[tid * 2], d1 = s_deg[tid * 2 + 1];
    s_ts[tid] = d0 + d1;
    __syncthreads();
    for (int ofs = 1; ofs < 256; ofs <<= 1) {
        int v = (tid >= ofs) ? s_ts[tid - ofs] : 0;
        __syncthreads();
        s_ts[tid] += v;
        __syncthreads();
    }
    int pre = tid ? s_ts[tid - 1] : 0;
    s_deg[tid * 2] = pbase + pre;
    s_deg[tid * 2 + 1] = pbase + pre + d0;
    __syncthreads();

    for (int l = tid; l < nn; l += 256) offs[n0 + l] = s_deg[l];
    if (bin == NBINS - 1 && tid == 0) offs[N_NODES] = N_EDGES;
    __syncthreads();

    for (int p = pbase + tid; p < pend; p += 256) {
        int4 pr = pairs[p];
        int pos = atomicAdd(&s_deg[pr.x - n0], 1);
        float2 ev = *(const float2*)(el + 2 * pr.y);
        rec[pos] = make_int4(pr.y, pr.z,
                             __float_as_int(ev.x), __float_as_int(ev.y));
    }
}

// ---------------------------------------------------------------------------
// K1: MFMA GEMM, merged: block = 64 rows, loops over all 6 (mat,half) slices.
// x-tile staged once (swizzled LDS); B-tile restaged per slice (L2-hot).
// grid (782). Block = 4 waves; wave = 16 rows x 64 cols per slice.
// ---------------------------------------------------------------------------
__global__ __launch_bounds__(256) void k_gemm_mfma(
    const unsigned short* __restrict__ xb, const unsigned short* __restrict__ wb,
    const float* __restrict__ skip_b,
    const float* __restrict__ al0, const float* __restrict__ ar0,
    const float* __restrict__ al1, const float* __restrict__ ar1,
    unsigned short* __restrict__ fb0, unsigned short* __restrict__ fb1,
    float* __restrict__ el0, float* __restrict__ er0,
    float* __restrict__ el1, float* __restrict__ er1,
    float* __restrict__ hs) {
    __shared__ unsigned short As[64][128];
    __shared__ unsigned short Bs[64][128];
    int tid = threadIdx.x;
    int m0 = blockIdx.x * 64;

    // stage A once, XOR-swizzled on 16B granules: seg ^= row&7
#pragma unroll
    for (int i = 0; i < 4; i++) {
        int idx = tid * 4 + i;
        int row = idx >> 4, seg = idx & 15;
        uint4 v = make_uint4(0, 0, 0, 0);
        int gr = m0 + row;
        if (gr < N_NODES) v = *(const uint4*)(xb + (size_t)gr * HID + seg * 8);
        *(uint4*)(&As[row][(seg ^ (row & 7)) * 8]) = v;
    }
    __syncthreads();

    int w = tid >> 6, l = tid & 63;
    int lr = l & 15, lg = l >> 4;
    int arow = w * 16 + lr;
    v8bf afrag[4];
#pragma unroll
    for (int kb = 0; kb < 4; kb++)
        afrag[kb] = *(v8bf*)(&As[arow][((kb * 4 + lg) ^ (arow & 7)) * 8]);

    for (int s = 0; s < 6; s++) {
        int mat = s >> 1;                 // 0=fc_w0, 1=fc_w1, 2=skip_w
        int j0 = (s & 1) * 64;
        __syncthreads();                  // prior slice's Bs reads complete
#pragma unroll
        for (int i = 0; i < 4; i++) {
            int idx = tid * 4 + i;
            int row = idx >> 4, seg = idx & 15;
            uint4 wv = *(const uint4*)(wb + (size_t)mat * 16384 +
                                       (size_t)(j0 + row) * HID + seg * 8);
            *(uint4*)(&Bs[row][(seg ^ (row & 7)) * 8]) = wv;
        }
        __syncthreads();

        v4f acc[4] = {};
#pragma unroll
        for (int nt = 0; nt < 4; nt++) {
            int brow = nt * 16 + lr;
#pragma unroll
            for (int kb = 0; kb < 4; kb++) {
                v8bf bfrag =
                    *(v8bf*)(&Bs[brow][((kb * 4 + lg) ^ (brow & 7)) * 8]);
                acc[nt] = __builtin_amdgcn_mfma_f32_16x16x32_bf16(
                    afrag[kb], bfrag, acc[nt], 0, 0, 0);
            }
        }

        // C/D layout: col = lane&15, row = (lane>>4)*4 + r   [m89-verified]
        if (mat < 2) {
            int h = s & 1;
            const float* al = mat ? al1 : al0;
            const float* ar = mat ? ar1 : ar0;
            float* elp = mat ? el1 : el0;
            float* erp = mat ? er1 : er0;
            unsigned short* fbp = mat ? fb1 : fb0;
            float elv[4] = {0.f, 0.f, 0.f, 0.f};
            float erv[4] = {0.f, 0.f, 0.f, 0.f};
#pragma unroll
            for (int nt = 0; nt < 4; nt++) {
                int colg = j0 + nt * 16 + lr;
                float av = al[colg], rv = ar[colg];
#pragma unroll
                for (int r = 0; r < 4; r++) {
                    elv[r] += acc[nt][r] * av;
                    erv[r] += acc[nt][r] * rv;
                }
            }
#pragma unroll
            for (int m = 1; m < 16; m <<= 1)
#pragma unroll
                for (int r = 0; r < 4; r++) {
                    elv[r] += __shfl_xor(elv[r], m);
                    erv[r] += __shfl_xor(erv[r], m);
                }
#pragma unroll
            for (int r = 0; r < 4; r++) {
                int grow = m0 + w * 16 + lg * 4 + r;
                if (grow >= N_NODES) continue;
#pragma unroll
                for (int nt = 0; nt < 4; nt++) {
                    int colg = j0 + nt * 16 + lr;
                    fbp[(size_t)grow * HID + colg] = f2b(acc[nt][r]);
                }
                if (lr == 0) {
                    elp[grow * 2 + h] = elv[r];
                    erp[grow * 2 + h] = erv[r];
                }
            }
        } else {
#pragma unroll
            for (int r = 0; r < 4; r++) {
                int grow = m0 + w * 16 + lg * 4 + r;
                if (grow >= N_NODES) continue;
#pragma unroll
                for (int nt = 0; nt < 4; nt++) {
                    int colg = j0 + nt * 16 + lr;
                    hs[(size_t)grow * HID + colg] = acc[nt][r] + skip_b[colg];
                }
            }
        }
    }
}

// ---------------------------------------------------------------------------
// K_aggregate: wave per dst node. Sequential 16B edge records; gather loop
// processes 4 edges/iter (16 lanes x 16B per edge). Writes h in place.
// ---------------------------------------------------------------------------
__device__ __forceinline__ void agg_rel2(const int* __restrict__ offs,
                                         const int4* __restrict__ rec,
                                         const float* __restrict__ er,
                                         const unsigned short* __restrict__ fb,
                                         int n, int lane, int cb, int sub,
                                         int hh, float* a) {
    int b = offs[n];
    int e_end = offs[n + 1];
    int deg = e_end - b;
    if (deg <= 0) return;
    float ern0 = er[2 * n], ern1 = er[2 * n + 1];

    const int NC = 4;
    int cs[NC];
    float cw0[NC], cw1[NC];
    float d0 = 0.f, d1 = 0.f;
    int nchunk = (deg + 63) >> 6;
    for (int ch = 0; ch < nchunk; ch++) {
        int p = b + (ch << 6) + lane;
        int s = 0;
        float w0 = 0.f, w1 = 0.f;
        if (p < e_end) {
            int4 r = rec[p];
            s = r.x;
            float wgt = __int_as_float(r.y);
            float x0 = expf(leaky(__int_as_float(r.z) + ern0));
            float x1 = expf(leaky(__int_as_float(r.w) + ern1));
            d0 += x0;
            d1 += x1;
            w0 = x0 * wgt;
            w1 = x1 * wgt;
        }
        if (ch < NC) {
            cs[ch] = s;
            cw0[ch] = w0;
            cw1[ch] = w1;
        }
    }
#pragma unroll
    for (int m = 32; m; m >>= 1) {
        d0 += __shfl_xor(d0, m);
        d1 += __shfl_xor(d1, m);
    }
    float invh = 1.f / (hh ? d1 : d0);

    for (int ch = 0; ch < nchunk; ch++) {
        int s;
        float w0, w1;
        if (ch < NC) {
            s = cs[ch];
            w0 = cw0[ch];
            w1 = cw1[ch];
        } else {
            int p = b + (ch << 6) + lane;
            s = 0;
            w0 = 0.f;
            w1 = 0.f;
            if (p < e_end) {
                int4 r = rec[p];
                s = r.x;
                float wgt = __int_as_float(r.y);
                w0 = expf(leaky(__int_as_float(r.z) + ern0)) * wgt;
                w1 = expf(leaky(__int_as_float(r.w) + ern1)) * wgt;
            }
        }
        int cnt = deg - (ch << 6);
        if (cnt > 64) cnt = 64;
        int ng = (cnt + 3) >> 2;
        for (int g = 0; g < ng; g++) {
            int sl = (g << 2) + sub;
            int sj = __shfl(s, sl);
            float w0j = __shfl(w0, sl);
            float w1j = __shfl(w1, sl);
            float aj = (hh ? w1j : w0j) * invh;
            uint4 fv = *(const uint4*)(fb + (size_t)sj * HID + cb * 8);
            a[0] += aj * __uint_as_float(fv.x << 16);
            a[1] += aj * __uint_as_float(fv.x & 0xffff0000u);
            a[2] += aj * __uint_as_float(fv.y << 16);
            a[3] += aj * __uint_as_float(fv.y & 0xffff0000u);
            a[4] += aj * __uint_as_float(fv.z << 16);
            a[5] += aj * __uint_as_float(fv.z & 0xffff0000u);
            a[6] += aj * __uint_as_float(fv.w << 16);
            a[7] += aj * __uint_as_float(fv.w & 0xffff0000u);
        }
    }
}

__global__ __launch_bounds__(256) void k_aggregate(
    const int* __restrict__ offs0, const int4* __restrict__ rec0,
    const float* __restrict__ er0, const unsigned short* __restrict__ fb0,
    const int* __restrict__ offs1, const int4* __restrict__ rec1,
    const float* __restrict__ er1, const unsigned short* __restrict__ fb1,
    const float* __restrict__ bias0, const float* __restrict__ bias1,
    float* __restrict__ h) {
    int wave = threadIdx.x >> 6, lane = threadIdx.x & 63;
    int n = blockIdx.x * 4 + wave;
    if (n >= N_NODES) return;
    int cb = lane & 15;        // col block: cols cb*8 .. cb*8+7
    int sub = lane >> 4;       // sub-edge slot
    int hh = cb >> 3;          // head of these cols
    float a[8] = {0.f, 0.f, 0.f, 0.f, 0.f, 0.f, 0.f, 0.f};
    agg_rel2(offs0, rec0, er0, fb0, n, lane, cb, sub, hh, a);
    agg_rel2(offs1, rec1, er1, fb1, n, lane, cb, sub, hh, a);
#pragma unroll
    for (int j = 0; j < 8; j++) {
        a[j] += __shfl_xor(a[j], 16);
        a[j] += __shfl_xor(a[j], 32);
    }
    if (sub == 0) {
        size_t base = (size_t)n * HID + cb * 8;
        float4 v0 = *(const float4*)(h + base);
        float4 v1 = *(const float4*)(h + base + 4);
        int c0 = cb * 8;
        float4 o0, o1;
        o0.x = v0.x + fmaxf(a[0] + bias0[c0 + 0] + bias1[c0 + 0], 0.f);
        o0.y = v0.y + fmaxf(a[1] + bias0[c0 + 1] + bias1[c0 + 1], 0.f);
        o0.z = v0.z + fmaxf(a[2] + bias0[c0 + 2] + bias1[c0 + 2], 0.f);
        o0.w = v0.w + fmaxf(a[3] + bias0[c0 + 3] + bias1[c0 + 3], 0.f);
        o1.x = v1.x + fmaxf(a[4] + bias0[c0 + 4] + bias1[c0 + 4], 0.f);
        o1.y = v1.y + fmaxf(a[5] + bias0[c0 + 5] + bias1[c0 + 5], 0.f);
        o1.z = v1.z + fmaxf(a[6] + bias0[c0 + 6] + bias1[c0 + 6], 0.f);
        o1.w = v1.w + fmaxf(a[7] + bias0[c0 + 7] + bias1[c0 + 7], 0.f);
        *(float4*)(h + base) = o0;
        *(float4*)(h + base + 4) = o1;
    }
}

// ---------------------------------------------------------------------------
// K_bnstats: per-column partial sums over h. EXACTLY 512 blocks x 256 threads.
// ---------------------------------------------------------------------------
__global__ __launch_bounds__(256) void k_bnstats(const float* __restrict__ h,
                                                 double* __restrict__ psum,
                                                 double* __restrict__ psumsq) {
    int tid = threadIdx.x;
    double s = 0.0, q = 0.0;
    const int total = N_NODES * HID;
    const int stride = 512 * 256;
    for (int idx = blockIdx.x * 256 + tid; idx < total; idx += stride) {
        float v = h[idx];
        s += v;
        q += (double)v * v;
    }
    __shared__ double ls[256], lq[256];
    ls[tid] = s;
    lq[tid] = q;
    __syncthreads();
    if (tid < 128) {
        psum[blockIdx.x * 128 + tid] = ls[tid] + ls[tid + 128];
        psumsq[blockIdx.x * 128 + tid] = lq[tid] + lq[tid + 128];
    }
}

__global__ void k_bn_finalize(const double* __restrict__ psum,
                              const double* __restrict__ psumsq,
                              const float* __restrict__ gamma,
                              const float* __restrict__ beta,
                              float* __restrict__ ss) {
    int c = threadIdx.x;
    double s = 0.0, q = 0.0;
    for (int b = 0; b < 512; b++) {
        s += psum[b * 128 + c];
        q += psumsq[b * 128 + c];
    }
    double mu = s / N_NODES;
    double var = q / N_NODES - mu * mu;
    float sc = gamma[c] * (float)(1.0 / sqrt(var + (double)BN_EPS));
    ss[c] = sc;
    ss[128 + c] = beta[c] - (float)mu * sc;
}

__global__ __launch_bounds__(256) void k_classify(const float* __restrict__ h,
                                                  const float* __restrict__ ss,
                                                  const float* __restrict__ clf_w,
                                                  const float* __restrict__ clf_b,
                                                  float* __restrict__ out) {
    int wave = threadIdx.x >> 6, lane = threadIdx.x & 63;
    int n = blockIdx.x * 4 + wave;
    if (n >= N_NODES) return;
    float v0 = h[(size_t)n * HID + lane] * ss[lane] + ss[128 + lane];
    float v1 = h[(size_t)n * HID + 64 + lane] * ss[64 + lane] + ss[192 + lane];
    v0 = fmaxf(v0, 0.f);
    v1 = fmaxf(v1, 0.f);
#pragma unroll
    for (int k = 0; k < 16; k++) {
        float p = v0 * clf_w[k * 128 + lane] + v1 * clf_w[k * 128 + 64 + lane];
#pragma unroll
        for (int m = 32; m; m >>= 1) p += __shfl_xor(p, m);
        if (lane == 0) out[(size_t)n * 16 + k] = p + clf_b[k];
    }
}

// ---------------------------------------------------------------------------
extern "C" void kernel_launch(void* const* d_in, const int* in_sizes, int n_in,
                              void* d_out, int out_size, void* d_ws, size_t ws_size,
                              hipStream_t stream) {
    (void)in_sizes; (void)n_in; (void)out_size; (void)ws_size;
    const float* x      = (const float*)d_in[0];
    const int*   src0   = (const int*)d_in[1];
    const int*   dst0   = (const int*)d_in[2];
    const float* ew0    = (const float*)d_in[3];
    const int*   src1   = (const int*)d_in[4];
    const int*   dst1   = (const int*)d_in[5];
    const float* ew1    = (const float*)d_in[6];
    const float* fc_w0  = (const float*)d_in[7];
    const float* bias0  = (const float*)d_in[8];
    const float* al0    = (const float*)d_in[9];
    const float* ar0    = (const float*)d_in[10];
    const float* fc_w1  = (const float*)d_in[11];
    const float* bias1  = (const float*)d_in[12];
    const float* al1    = (const float*)d_in[13];
    const float* ar1    = (const float*)d_in[14];
    const float* skip_w = (const float*)d_in[15];
    const float* skip_b = (const float*)d_in[16];
    const float* gamma  = (const float*)d_in[17];
    const float* beta   = (const float*)d_in[18];
    const float* clf_w  = (const float*)d_in[19];
    const float* clf_b  = (const float*)d_in[20];
    float* out = (float*)d_out;

    char* wsp = (char*)d_ws;
    size_t off = 0;
    auto alloc = [&](size_t bytes) -> char* {
        char* p = wsp + off;
        off += (bytes + 255) & ~(size_t)255;
        return p;
    };
    unsigned short* xb  = (unsigned short*)alloc((size_t)N_NODES * HID * 2);
    unsigned short* wb  = (unsigned short*)alloc((size_t)3 * 16384 * 2);
    unsigned short* fb0 = (unsigned short*)alloc((size_t)N_NODES * HID * 2);
    unsigned short* fb1 = (unsigned short*)alloc((size_t)N_NODES * HID * 2);
    float*  hs     = (float*)alloc((size_t)N_NODES * HID * 4);   // becomes h
    float*  el0    = (float*)alloc((size_t)N_NODES * 2 * 4);
    float*  er0    = (float*)alloc((size_t)N_NODES * 2 * 4);
    float*  el1    = (float*)alloc((size_t)N_NODES * 2 * 4);
    float*  er1    = (float*)alloc((size_t)N_NODES * 2 * 4);
    int*    bincnt = (int*)alloc((size_t)2 * NBINS * NBLK * 4);
    int4*   pairs0 = (int4*)alloc((size_t)N_EDGES * 16);
    int4*   pairs1 = (int4*)alloc((size_t)N_EDGES * 16);
    int*    offs0  = (int*)alloc((size_t)(N_NODES + 1) * 4);
    int*    offs1  = (int*)alloc((size_t)(N_NODES + 1) * 4);
    int4*   rec0   = (int4*)alloc((size_t)N_EDGES * 16);
    int4*   rec1   = (int4*)alloc((size_t)N_EDGES * 16);
    double* psum   = (double*)alloc((size_t)512 * 128 * 8);
    double* psumsq = (double*)alloc((size_t)512 * 128 * 8);
    float*  ss     = (float*)alloc(256 * 4);

    // bf16 conversion of x and weights
    k_prep<<<6299, 256, 0, stream>>>(x, fc_w0, fc_w1, skip_w, xb, wb);

    // CSR binning (independent of GEMM)
    dim3 gbin(NBLK, 2);
    k_bincount<<<gbin, 256, 0, stream>>>(dst0, dst1, bincnt);
    k_binscan<<<2, 1024, 0, stream>>>(bincnt);
    k_binscatter<<<gbin, 256, 0, stream>>>(dst0, dst1, src0, src1, ew0, ew1,
                                           bincnt, pairs0, pairs1);

    // MFMA GEMM (merged slices) + fused attention dots + bf16 tables + hs
    k_gemm_mfma<<<(N_NODES + 63) / 64, 256, 0, stream>>>(
        xb, wb, skip_b, al0, ar0, al1, ar1,
        fb0, fb1, el0, er0, el1, er1, hs);

    // CSR finalize: sorted 16B edge records (needs el)
    dim3 gcsr(NBINS, 2);
    k_csr<<<gcsr, 256, 0, stream>>>(bincnt, pairs0, pairs1, el0, el1,
                                    offs0, offs1, rec0, rec1);

    // gather aggregation, h = hs + relu(bias + msgs) in place
    k_aggregate<<<(N_NODES + 3) / 4, 256, 0, stream>>>(
        offs0, rec0, er0, fb0, offs1, rec1, er1, fb1, bias0, bias1, hs);

    k_bnstats<<<512, 256, 0, stream>>>(hs, psum, psumsq);
    k_bn_finalize<<<1, 128, 0, stream>>>(psum, psumsq, gamma, beta, ss);
    k_classify<<<(N_NODES + 3) / 4, 256, 0, stream>>>(hs, ss, clf_w, clf_b, out);
}

// Round 7
// 235.336 us; speedup vs baseline: 4.3736x; 1.1851x over previous
//
#include <hip/hip_runtime.h>
#include <hip/hip_bf16.h>

// Problem constants (match reference)
#define N_NODES 50000
#define N_EDGES 800000
#define HID 128          // HEADS*HEAD_DIM
#define NEG_SLOPE 0.2f
#define BN_EPS 1e-5f

// CSR binning parameters
#define NBLK 256         // blocks over edges
#define BINSZ 512        // nodes per bin (power of 2)
#define BINSH 9
#define NBINS 98         // ceil(N_NODES / BINSZ)

typedef __bf16 v8bf __attribute__((ext_vector_type(8)));
typedef float v4f __attribute__((ext_vector_type(4)));

__device__ __forceinline__ float leaky(float v) {
    return (v > 0.f) ? v : v * NEG_SLOPE;
}
__device__ __forceinline__ unsigned int f2bu(float f) {
    __hip_bfloat16 b = __float2bfloat16(f);
    return (unsigned int)*reinterpret_cast<unsigned short*>(&b);
}
__device__ __forceinline__ unsigned int pack2bf(float lo, float hi) {
    return f2bu(lo) | (f2bu(hi) << 16);
}

// ---------------------------------------------------------------------------
// CSR pass A: per-block LDS histogram of dst bins. grid: (NBLK, 2)
// ---------------------------------------------------------------------------
__global__ __launch_bounds__(256) void k_bincount(const int* __restrict__ dst0,
                                                  const int* __restrict__ dst1,
                                                  int* __restrict__ bincnt) {
    int rel = blockIdx.y;
    const int* dst = rel ? dst1 : dst0;
    __shared__ int cnt[NBINS];
    for (int i = threadIdx.x; i < NBINS; i += 256) cnt[i] = 0;
    __syncthreads();
    const int CH = (N_EDGES + NBLK - 1) / NBLK;   // 3125
    int b0 = blockIdx.x * CH;
    int b1 = min(N_EDGES, b0 + CH);
    for (int e = b0 + threadIdx.x; e < b1; e += 256)
        atomicAdd(&cnt[dst[e] >> BINSH], 1);
    __syncthreads();
    for (int i = threadIdx.x; i < NBINS; i += 256)
        bincnt[rel * NBINS * NBLK + i * NBLK + blockIdx.x] = cnt[i];
}

// ---------------------------------------------------------------------------
// CSR pass B: in-place exclusive scan of bincnt per relation. grid: (2)
// ---------------------------------------------------------------------------
__global__ __launch_bounds__(1024) void k_binscan(int* __restrict__ bincnt) {
    int* a = bincnt + blockIdx.x * NBINS * NBLK;
    const int TOT = NBINS * NBLK;                 // 25088
    const int CH = (TOT + 1023) / 1024;           // 25
    int tid = threadIdx.x;
    int base = tid * CH;
    int lv[CH];
    int sum = 0;
    for (int i = 0; i < CH; i++) {
        int idx = base + i;
        int v = (idx < TOT) ? a[idx] : 0;
        lv[i] = sum;
        sum += v;
    }
    __shared__ int ls[1024];
    ls[tid] = sum;
    __syncthreads();
    for (int ofs = 1; ofs < 1024; ofs <<= 1) {
        int v = (tid >= ofs) ? ls[tid - ofs] : 0;
        __syncthreads();
        ls[tid] += v;
        __syncthreads();
    }
    int pre = tid ? ls[tid - 1] : 0;
    for (int i = 0; i < CH; i++) {
        int idx = base + i;
        if (idx < TOT) a[idx] = pre + lv[i];
    }
}

// ---------------------------------------------------------------------------
// CSR pass C: scatter packed (dst_local|src<<9, ew) 8B pairs into
// per-(bin,block) contiguous runs. grid: (NBLK, 2)
// ---------------------------------------------------------------------------
__global__ __launch_bounds__(256) void k_binscatter(const int* __restrict__ dst0,
                                                    const int* __restrict__ dst1,
                                                    const int* __restrict__ src0,
                                                    const int* __restrict__ src1,
                                                    const float* __restrict__ ew0,
                                                    const float* __restrict__ ew1,
                                                    const int* __restrict__ bincnt,
                                                    int2* __restrict__ pairs0,
                                                    int2* __restrict__ pairs1) {
    int rel = blockIdx.y;
    const int* dst = rel ? dst1 : dst0;
    const int* src = rel ? src1 : src0;
    const float* ew = rel ? ew1 : ew0;
    int2* pairs = rel ? pairs1 : pairs0;
    __shared__ int cur[NBINS];
    for (int i = threadIdx.x; i < NBINS; i += 256)
        cur[i] = bincnt[rel * NBINS * NBLK + i * NBLK + blockIdx.x];
    __syncthreads();
    const int CH = (N_EDGES + NBLK - 1) / NBLK;
    int b0 = blockIdx.x * CH;
    int b1 = min(N_EDGES, b0 + CH);
    for (int e = b0 + threadIdx.x; e < b1; e += 256) {
        int d = dst[e];
        int pos = atomicAdd(&cur[d >> BINSH], 1);
        unsigned int packed = (unsigned int)(d & (BINSZ - 1)) |
                              ((unsigned int)src[e] << BINSH);
        pairs[pos] = make_int2((int)packed, __float_as_int(ew[e]));
    }
}

// ---------------------------------------------------------------------------
// CSR pass D: per (rel,bin): LDS histogram -> scan -> offs (+sentinel) ->
// place 16B edge records (src, ew, el0, el1) sorted by dst. grid: (NBINS, 2)
// Runs AFTER the GEMM (needs el). Only el is a random gather (8B/edge).
// ---------------------------------------------------------------------------
__global__ __launch_bounds__(256) void k_csr(const int* __restrict__ bincnt,
                                             const int2* __restrict__ pairs0,
                                             const int2* __restrict__ pairs1,
                                             const float* __restrict__ el0,
                                             const float* __restrict__ el1,
                                             int* __restrict__ offs0,
                                             int* __restrict__ offs1,
                                             int4* __restrict__ rec0,
                                             int4* __restrict__ rec1) {
    int rel = blockIdx.y;
    const int2* pairs = rel ? pairs1 : pairs0;
    const float* el = rel ? el1 : el0;
    int* offs = rel ? offs1 : offs0;
    int4* rec = rel ? rec1 : rec0;
    int bin = blockIdx.x;
    int tid = threadIdx.x;
    const int* bc = bincnt + rel * NBINS * NBLK;
    int pbase = bc[bin * NBLK];
    int pend = (bin < NBINS - 1) ? bc[(bin + 1) * NBLK] : N_EDGES;
    int n0 = bin << BINSH;
    int nn = min(N_NODES - n0, BINSZ);

    __shared__ int s_deg[BINSZ];
    __shared__ int s_ts[256];
    for (int i = tid; i < BINSZ; i += 256) s_deg[i] = 0;
    __syncthreads();
    for (int p = pbase + tid; p < pend; p += 256)
        atomicAdd(&s_deg[((unsigned int)pairs[p].x) & (BINSZ - 1)], 1);
    __syncthreads();

    int d0 = s_deg[tid * 2], d1 = s_deg[tid * 2 + 1];
    s_ts[tid] = d0 + d1;
    __syncthreads();
    for (int ofs = 1; ofs < 256; ofs <<= 1) {
        int v = (tid >= ofs) ? s_ts[tid - ofs] : 0;
        __syncthreads();
        s_ts[tid] += v;
        __syncthreads();
    }
    int pre = tid ? s_ts[tid - 1] : 0;
    s_deg[tid * 2] = pbase + pre;
    s_deg[tid * 2 + 1] = pbase + pre + d0;
    __syncthreads();

    for (int l = tid; l < nn; l += 256) offs[n0 + l] = s_deg[l];
    if (bin == NBINS - 1 && tid == 0) offs[N_NODES] = N_EDGES;
    __syncthreads();

    for (int p = pbase + tid; p < pend; p += 256) {
        int2 pr = pairs[p];
        unsigned int u = (unsigned int)pr.x;
        int dl = (int)(u & (BINSZ - 1));
        int s = (int)(u >> BINSH);
        int pos = atomicAdd(&s_deg[dl], 1);
        float2 ev = *(const float2*)(el + 2 * s);
        rec[pos] = make_int4(s, pr.y,
                             __float_as_int(ev.x), __float_as_int(ev.y));
    }
}

// ---------------------------------------------------------------------------
// K1: MFMA GEMM, merged: block = 64 rows, loops over all 6 (mat,half) slices.
// f32 inputs converted to bf16 in-register during staging (k_prep folded in).
// grid (782). Block = 4 waves; wave = 16 rows x 64 cols per slice.
// ---------------------------------------------------------------------------
__global__ __launch_bounds__(256) void k_gemm_mfma(
    const float* __restrict__ x,
    const float* __restrict__ w0, const float* __restrict__ w1,
    const float* __restrict__ wsk, const float* __restrict__ skip_b,
    const float* __restrict__ al0, const float* __restrict__ ar0,
    const float* __restrict__ al1, const float* __restrict__ ar1,
    unsigned short* __restrict__ fb0, unsigned short* __restrict__ fb1,
    float* __restrict__ el0, float* __restrict__ er0,
    float* __restrict__ el1, float* __restrict__ er1,
    float* __restrict__ hs) {
    __shared__ unsigned short As[64][128];
    __shared__ unsigned short Bs[64][128];
    int tid = threadIdx.x;
    int m0 = blockIdx.x * 64;

    // stage A once from f32, convert, XOR-swizzle on 16B granules
#pragma unroll
    for (int i = 0; i < 4; i++) {
        int idx = tid * 4 + i;
        int row = idx >> 4, seg = idx & 15;
        int gr = m0 + row;
        uint4 o = make_uint4(0, 0, 0, 0);
        if (gr < N_NODES) {
            const float* p = x + (size_t)gr * HID + seg * 8;
            float4 p0 = *(const float4*)p;
            float4 p1 = *(const float4*)(p + 4);
            o.x = pack2bf(p0.x, p0.y);
            o.y = pack2bf(p0.z, p0.w);
            o.z = pack2bf(p1.x, p1.y);
            o.w = pack2bf(p1.z, p1.w);
        }
        *(uint4*)(&As[row][(seg ^ (row & 7)) * 8]) = o;
    }
    __syncthreads();

    int w = tid >> 6, l = tid & 63;
    int lr = l & 15, lg = l >> 4;
    int arow = w * 16 + lr;
    v8bf afrag[4];
#pragma unroll
    for (int kb = 0; kb < 4; kb++)
        afrag[kb] = *(v8bf*)(&As[arow][((kb * 4 + lg) ^ (arow & 7)) * 8]);

    for (int s = 0; s < 6; s++) {
        int mat = s >> 1;                 // 0=fc_w0, 1=fc_w1, 2=skip_w
        int j0 = (s & 1) * 64;
        const float* W = (mat == 0) ? w0 : (mat == 1) ? w1 : wsk;
        __syncthreads();                  // prior slice's Bs reads complete
#pragma unroll
        for (int i = 0; i < 4; i++) {
            int idx = tid * 4 + i;
            int row = idx >> 4, seg = idx & 15;
            const float* p = W + (size_t)(j0 + row) * HID + seg * 8;
            float4 p0 = *(const float4*)p;
            float4 p1 = *(const float4*)(p + 4);
            uint4 o;
            o.x = pack2bf(p0.x, p0.y);
            o.y = pack2bf(p0.z, p0.w);
            o.z = pack2bf(p1.x, p1.y);
            o.w = pack2bf(p1.z, p1.w);
            *(uint4*)(&Bs[row][(seg ^ (row & 7)) * 8]) = o;
        }
        __syncthreads();

        v4f acc[4] = {};
#pragma unroll
        for (int nt = 0; nt < 4; nt++) {
            int brow = nt * 16 + lr;
#pragma unroll
            for (int kb = 0; kb < 4; kb++) {
                v8bf bfrag =
                    *(v8bf*)(&Bs[brow][((kb * 4 + lg) ^ (brow & 7)) * 8]);
                acc[nt] = __builtin_amdgcn_mfma_f32_16x16x32_bf16(
                    afrag[kb], bfrag, acc[nt], 0, 0, 0);
            }
        }

        // C/D layout: col = lane&15, row = (lane>>4)*4 + r   [m89-verified]
        if (mat < 2) {
            int h = s & 1;
            const float* al = mat ? al1 : al0;
            const float* ar = mat ? ar1 : ar0;
            float* elp = mat ? el1 : el0;
            float* erp = mat ? er1 : er0;
            unsigned short* fbp = mat ? fb1 : fb0;
            float elv[4] = {0.f, 0.f, 0.f, 0.f};
            float erv[4] = {0.f, 0.f, 0.f, 0.f};
#pragma unroll
            for (int nt = 0; nt < 4; nt++) {
                int colg = j0 + nt * 16 + lr;
                float av = al[colg], rv = ar[colg];
#pragma unroll
                for (int r = 0; r < 4; r++) {
                    elv[r] += acc[nt][r] * av;
                    erv[r] += acc[nt][r] * rv;
                }
            }
#pragma unroll
            for (int m = 1; m < 16; m <<= 1)
#pragma unroll
                for (int r = 0; r < 4; r++) {
                    elv[r] += __shfl_xor(elv[r], m);
                    erv[r] += __shfl_xor(erv[r], m);
                }
#pragma unroll
            for (int r = 0; r < 4; r++) {
                int grow = m0 + w * 16 + lg * 4 + r;
                if (grow >= N_NODES) continue;
#pragma unroll
                for (int nt = 0; nt < 4; nt++) {
                    int colg = j0 + nt * 16 + lr;
                    fbp[(size_t)grow * HID + colg] =
                        (unsigned short)f2bu(acc[nt][r]);
                }
                if (lr == 0) {
                    elp[grow * 2 + h] = elv[r];
                    erp[grow * 2 + h] = erv[r];
                }
            }
        } else {
#pragma unroll
            for (int r = 0; r < 4; r++) {
                int grow = m0 + w * 16 + lg * 4 + r;
                if (grow >= N_NODES) continue;
#pragma unroll
                for (int nt = 0; nt < 4; nt++) {
                    int colg = j0 + nt * 16 + lr;
                    hs[(size_t)grow * HID + colg] = acc[nt][r] + skip_b[colg];
                }
            }
        }
    }
}

// ---------------------------------------------------------------------------
// K_aggregate: wave per dst node. Sequential 16B edge records; alpha packed
// as bf16x2 (head0|head1) -> inner loop = 2 shfl + select. h in place.
// ---------------------------------------------------------------------------
__device__ __forceinline__ void agg_rel2(const int* __restrict__ offs,
                                         const int4* __restrict__ rec,
                                         const float* __restrict__ er,
                                         const unsigned short* __restrict__ fb,
                                         int n, int lane, int cb, int sub,
                                         int hh, float* a) {
    int b = offs[n];
    int e_end = offs[n + 1];
    int deg = e_end - b;
    if (deg <= 0) return;
    float ern0 = er[2 * n], ern1 = er[2 * n + 1];

    const int NC = 4;
    int cs[NC];
    float cw0[NC], cw1[NC];
    unsigned int cpk[NC];
    float d0 = 0.f, d1 = 0.f;
    int nchunk = (deg + 63) >> 6;
    for (int ch = 0; ch < nchunk; ch++) {
        int p = b + (ch << 6) + lane;
        int s = 0;
        float w0 = 0.f, w1 = 0.f;
        if (p < e_end) {
            int4 r = rec[p];
            s = r.x;
            float wgt = __int_as_float(r.y);
            float x0 = expf(leaky(__int_as_float(r.z) + ern0));
            float x1 = expf(leaky(__int_as_float(r.w) + ern1));
            d0 += x0;
            d1 += x1;
            w0 = x0 * wgt;
            w1 = x1 * wgt;
        }
        if (ch < NC) {
            cs[ch] = s;
            cw0[ch] = w0;
            cw1[ch] = w1;
        }
    }
#pragma unroll
    for (int m = 32; m; m >>= 1) {
        d0 += __shfl_xor(d0, m);
        d1 += __shfl_xor(d1, m);
    }
    float inv0 = 1.f / d0, inv1 = 1.f / d1;
#pragma unroll
    for (int ch = 0; ch < NC; ch++)
        cpk[ch] = pack2bf(cw0[ch] * inv0, cw1[ch] * inv1);

    for (int ch = 0; ch < nchunk; ch++) {
        int s;
        unsigned int pk;
        if (ch < NC) {
            s = cs[ch];
            pk = cpk[ch];
        } else {
            int p = b + (ch << 6) + lane;
            s = 0;
            pk = 0;
            if (p < e_end) {
                int4 r = rec[p];
                s = r.x;
                float wgt = __int_as_float(r.y);
                float w0 = expf(leaky(__int_as_float(r.z) + ern0)) * wgt;
                float w1 = expf(leaky(__int_as_float(r.w) + ern1)) * wgt;
                pk = pack2bf(w0 * inv0, w1 * inv1);
            }
        }
        int cnt = deg - (ch << 6);
        if (cnt > 64) cnt = 64;
        int ng = (cnt + 3) >> 2;
#pragma unroll 2
        for (int g = 0; g < ng; g++) {
            int sl = (g << 2) + sub;
            int sj = __shfl(s, sl);
            unsigned int pkj = (unsigned int)__shfl((int)pk, sl);
            float aj = __uint_as_float(hh ? (pkj & 0xffff0000u) : (pkj << 16));
            uint4 fv = *(const uint4*)(fb + (size_t)sj * HID + cb * 8);
            a[0] += aj * __uint_as_float(fv.x << 16);
            a[1] += aj * __uint_as_float(fv.x & 0xffff0000u);
            a[2] += aj * __uint_as_float(fv.y << 16);
            a[3] += aj * __uint_as_float(fv.y & 0xffff0000u);
            a[4] += aj * __uint_as_float(fv.z << 16);
            a[5] += aj * __uint_as_float(fv.z & 0xffff0000u);
            a[6] += aj * __uint_as_float(fv.w << 16);
            a[7] += aj * __uint_as_float(fv.w & 0xffff0000u);
        }
    }
}

__global__ __launch_bounds__(256) void k_aggregate(
    const int* __restrict__ offs0, const int4* __restrict__ rec0,
    const float* __restrict__ er0, const unsigned short* __restrict__ fb0,
    const int* __restrict__ offs1, const int4* __restrict__ rec1,
    const float* __restrict__ er1, const unsigned short* __restrict__ fb1,
    const float* __restrict__ bias0, const float* __restrict__ bias1,
    float* __restrict__ h) {
    int wave = threadIdx.x >> 6, lane = threadIdx.x & 63;
    int n = blockIdx.x * 4 + wave;
    if (n >= N_NODES) return;
    int cb = lane & 15;        // col block: cols cb*8 .. cb*8+7
    int sub = lane >> 4;       // sub-edge slot
    int hh = cb >> 3;          // head of these cols
    float a[8] = {0.f, 0.f, 0.f, 0.f, 0.f, 0.f, 0.f, 0.f};
    agg_rel2(offs0, rec0, er0, fb0, n, lane, cb, sub, hh, a);
    agg_rel2(offs1, rec1, er1, fb1, n, lane, cb, sub, hh, a);
#pragma unroll
    for (int j = 0; j < 8; j++) {
        a[j] += __shfl_xor(a[j], 16);
        a[j] += __shfl_xor(a[j], 32);
    }
    if (sub == 0) {
        size_t base = (size_t)n * HID + cb * 8;
        float4 v0 = *(const float4*)(h + base);
        float4 v1 = *(const float4*)(h + base + 4);
        int c0 = cb * 8;
        float4 o0, o1;
        o0.x = v0.x + fmaxf(a[0] + bias0[c0 + 0] + bias1[c0 + 0], 0.f);
        o0.y = v0.y + fmaxf(a[1] + bias0[c0 + 1] + bias1[c0 + 1], 0.f);
        o0.z = v0.z + fmaxf(a[2] + bias0[c0 + 2] + bias1[c0 + 2], 0.f);
        o0.w = v0.w + fmaxf(a[3] + bias0[c0 + 3] + bias1[c0 + 3], 0.f);
        o1.x = v1.x + fmaxf(a[4] + bias0[c0 + 4] + bias1[c0 + 4], 0.f);
        o1.y = v1.y + fmaxf(a[5] + bias0[c0 + 5] + bias1[c0 + 5], 0.f);
        o1.z = v1.z + fmaxf(a[6] + bias0[c0 + 6] + bias1[c0 + 6], 0.f);
        o1.w = v1.w + fmaxf(a[7] + bias0[c0 + 7] + bias1[c0 + 7], 0.f);
        *(float4*)(h + base) = o0;
        *(float4*)(h + base + 4) = o1;
    }
}

// ---------------------------------------------------------------------------
// K_bnstats: per-column partial sums over h. EXACTLY 512 blocks x 256 threads.
// ---------------------------------------------------------------------------
__global__ __launch_bounds__(256) void k_bnstats(const float* __restrict__ h,
                                                 double* __restrict__ psum,
                                                 double* __restrict__ psumsq) {
    int tid = threadIdx.x;
    double s = 0.0, q = 0.0;
    const int total = N_NODES * HID;
    const int stride = 512 * 256;
    for (int idx = blockIdx.x * 256 + tid; idx < total; idx += stride) {
        float v = h[idx];
        s += v;
        q += (double)v * v;
    }
    __shared__ double ls[256], lq[256];
    ls[tid] = s;
    lq[tid] = q;
    __syncthreads();
    if (tid < 128) {
        psum[blockIdx.x * 128 + tid] = ls[tid] + ls[tid + 128];
        psumsq[blockIdx.x * 128 + tid] = lq[tid] + lq[tid + 128];
    }
}

__global__ void k_bn_finalize(const double* __restrict__ psum,
                              const double* __restrict__ psumsq,
                              const float* __restrict__ gamma,
                              const float* __restrict__ beta,
                              float* __restrict__ ss) {
    int c = threadIdx.x;
    double s = 0.0, q = 0.0;
    for (int b = 0; b < 512; b++) {
        s += psum[b * 128 + c];
        q += psumsq[b * 128 + c];
    }
    double mu = s / N_NODES;
    double var = q / N_NODES - mu * mu;
    float sc = gamma[c] * (float)(1.0 / sqrt(var + (double)BN_EPS));
    ss[c] = sc;
    ss[128 + c] = beta[c] - (float)mu * sc;
}

// ---------------------------------------------------------------------------
// K_classify: MFMA 16x16x32. Wave = 16 nodes x 16 classes, K=128.
// A = relu(h*sc+sh) -> bf16; B = clf_w -> bf16. grid 782 x 4 waves.
// ---------------------------------------------------------------------------
__global__ __launch_bounds__(256) void k_classify(const float* __restrict__ h,
                                                  const float* __restrict__ ss,
                                                  const float* __restrict__ clf_w,
                                                  const float* __restrict__ clf_b,
                                                  float* __restrict__ out) {
    int w = threadIdx.x >> 6, l = threadIdx.x & 63;
    int lr = l & 15, lg = l >> 4;
    int n0 = (blockIdx.x * 4 + w) * 16;
    if (n0 >= N_NODES) return;

    v8bf afrag[4], bfrag[4];
#pragma unroll
    for (int kb = 0; kb < 4; kb++) {
        int k0 = kb * 32 + lg * 8;
        // B: clf_w row = class lr
        const float* bp = clf_w + lr * HID + k0;
        float4 b0 = *(const float4*)bp;
        float4 b1 = *(const float4*)(bp + 4);
        bfrag[kb][0] = (__bf16)b0.x; bfrag[kb][1] = (__bf16)b0.y;
        bfrag[kb][2] = (__bf16)b0.z; bfrag[kb][3] = (__bf16)b0.w;
        bfrag[kb][4] = (__bf16)b1.x; bfrag[kb][5] = (__bf16)b1.y;
        bfrag[kb][6] = (__bf16)b1.z; bfrag[kb][7] = (__bf16)b1.w;
        // A: h row = node n0+lr, BN scale/shift + relu fused
        const float* ap = h + (size_t)(n0 + lr) * HID + k0;
        float4 a0 = *(const float4*)ap;
        float4 a1 = *(const float4*)(ap + 4);
        float4 sc0 = *(const float4*)(ss + k0);
        float4 sc1 = *(const float4*)(ss + k0 + 4);
        float4 sh0 = *(const float4*)(ss + 128 + k0);
        float4 sh1 = *(const float4*)(ss + 128 + k0 + 4);
        afrag[kb][0] = (__bf16)fmaxf(a0.x * sc0.x + sh0.x, 0.f);
        afrag[kb][1] = (__bf16)fmaxf(a0.y * sc0.y + sh0.y, 0.f);
        afrag[kb][2] = (__bf16)fmaxf(a0.z * sc0.z + sh0.z, 0.f);
        afrag[kb][3] = (__bf16)fmaxf(a0.w * sc0.w + sh0.w, 0.f);
        afrag[kb][4] = (__bf16)fmaxf(a1.x * sc1.x + sh1.x, 0.f);
        afrag[kb][5] = (__bf16)fmaxf(a1.y * sc1.y + sh1.y, 0.f);
        afrag[kb][6] = (__bf16)fmaxf(a1.z * sc1.z + sh1.z, 0.f);
        afrag[kb][7] = (__bf16)fmaxf(a1.w * sc1.w + sh1.w, 0.f);
    }
    v4f acc = {};
#pragma unroll
    for (int kb = 0; kb < 4; kb++)
        acc = __builtin_amdgcn_mfma_f32_16x16x32_bf16(afrag[kb], bfrag[kb],
                                                      acc, 0, 0, 0);
    float cb = clf_b[lr];
#pragma unroll
    for (int r = 0; r < 4; r++) {
        int n = n0 + lg * 4 + r;
        out[(size_t)n * 16 + lr] = acc[r] + cb;
    }
}

// ---------------------------------------------------------------------------
extern "C" void kernel_launch(void* const* d_in, const int* in_sizes, int n_in,
                              void* d_out, int out_size, void* d_ws, size_t ws_size,
                              hipStream_t stream) {
    (void)in_sizes; (void)n_in; (void)out_size; (void)ws_size;
    const float* x      = (const float*)d_in[0];
    const int*   src0   = (const int*)d_in[1];
    const int*   dst0   = (const int*)d_in[2];
    const float* ew0    = (const float*)d_in[3];
    const int*   src1   = (const int*)d_in[4];
    const int*   dst1   = (const int*)d_in[5];
    const float* ew1    = (const float*)d_in[6];
    const float* fc_w0  = (const float*)d_in[7];
    const float* bias0  = (const float*)d_in[8];
    const float* al0    = (const float*)d_in[9];
    const float* ar0    = (const float*)d_in[10];
    const float* fc_w1  = (const float*)d_in[11];
    const float* bias1  = (const float*)d_in[12];
    const float* al1    = (const float*)d_in[13];
    const float* ar1    = (const float*)d_in[14];
    const float* skip_w = (const float*)d_in[15];
    const float* skip_b = (const float*)d_in[16];
    const float* gamma  = (const float*)d_in[17];
    const float* beta   = (const float*)d_in[18];
    const float* clf_w  = (const float*)d_in[19];
    const float* clf_b  = (const float*)d_in[20];
    float* out = (float*)d_out;

    char* wsp = (char*)d_ws;
    size_t off = 0;
    auto alloc = [&](size_t bytes) -> char* {
        char* p = wsp + off;
        off += (bytes + 255) & ~(size_t)255;
        return p;
    };
    unsigned short* fb0 = (unsigned short*)alloc((size_t)N_NODES * HID * 2);
    unsigned short* fb1 = (unsigned short*)alloc((size_t)N_NODES * HID * 2);
    float*  hs     = (float*)alloc((size_t)N_NODES * HID * 4);   // becomes h
    float*  el0    = (float*)alloc((size_t)N_NODES * 2 * 4);
    float*  er0    = (float*)alloc((size_t)N_NODES * 2 * 4);
    float*  el1    = (float*)alloc((size_t)N_NODES * 2 * 4);
    float*  er1    = (float*)alloc((size_t)N_NODES * 2 * 4);
    int*    bincnt = (int*)alloc((size_t)2 * NBINS * NBLK * 4);
    int2*   pairs0 = (int2*)alloc((size_t)N_EDGES * 8);
    int2*   pairs1 = (int2*)alloc((size_t)N_EDGES * 8);
    int*    offs0  = (int*)alloc((size_t)(N_NODES + 1) * 4);
    int*    offs1  = (int*)alloc((size_t)(N_NODES + 1) * 4);
    int4*   rec0   = (int4*)alloc((size_t)N_EDGES * 16);
    int4*   rec1   = (int4*)alloc((size_t)N_EDGES * 16);
    double* psum   = (double*)alloc((size_t)512 * 128 * 8);
    double* psumsq = (double*)alloc((size_t)512 * 128 * 8);
    float*  ss     = (float*)alloc(256 * 4);

    // CSR binning (independent of GEMM)
    dim3 gbin(NBLK, 2);
    k_bincount<<<gbin, 256, 0, stream>>>(dst0, dst1, bincnt);
    k_binscan<<<2, 1024, 0, stream>>>(bincnt);
    k_binscatter<<<gbin, 256, 0, stream>>>(dst0, dst1, src0, src1, ew0, ew1,
                                           bincnt, pairs0, pairs1);

    // MFMA GEMM (merged slices, inline f32->bf16) + attention dots + hs
    k_gemm_mfma<<<(N_NODES + 63) / 64, 256, 0, stream>>>(
        x, fc_w0, fc_w1, skip_w, skip_b, al0, ar0, al1, ar1,
        fb0, fb1, el0, er0, el1, er1, hs);

    // CSR finalize: sorted 16B edge records (needs el)
    dim3 gcsr(NBINS, 2);
    k_csr<<<gcsr, 256, 0, stream>>>(bincnt, pairs0, pairs1, el0, el1,
                                    offs0, offs1, rec0, rec1);

    // gather aggregation, h = hs + relu(bias + msgs) in place
    k_aggregate<<<(N_NODES + 3) / 4, 256, 0, stream>>>(
        offs0, rec0, er0, fb0, offs1, rec1, er1, fb1, bias0, bias1, hs);

    k_bnstats<<<512, 256, 0, stream>>>(hs, psum, psumsq);
    k_bn_finalize<<<1, 128, 0, stream>>>(psum, psumsq, gamma, beta, ss);
    k_classify<<<(N_NODES + 15) / 16 / 4 + 1, 256, 0, stream>>>(
        hs, ss, clf_w, clf_b, out);
}